// Round 20
// baseline (129.473 us; speedup 1.0000x reference)
//
#include <hip/hip_runtime.h>
#include <math.h>

#define SEQ   2048
#define BATCH 2
#define NH    16
#define DKD   64
#define DM    1024
#define MTOT  (BATCH*SEQ)   // 4096

typedef short bf16x8 __attribute__((ext_vector_type(8)));      // 8 bf16 (4 VGPR)
typedef float f32x4  __attribute__((ext_vector_type(4)));      // MFMA C/D
typedef unsigned short u16x4 __attribute__((ext_vector_type(4)));
typedef unsigned short u16x8 __attribute__((ext_vector_type(8)));

#define MFMA_B16(a,b,c) __builtin_amdgcn_mfma_f32_16x16x32_bf16((a),(b),(c),0,0,0)

__device__ __forceinline__ unsigned short f2bf(float f) {
    union { float f; unsigned int u; } v; v.f = f;
    unsigned int r = v.u + 0x7FFFu + ((v.u >> 16) & 1u);   // RNE
    return (unsigned short)(r >> 16);
}
__device__ __forceinline__ float bf2f(unsigned short h) {
    union { unsigned int u; float f; } v; v.u = ((unsigned int)h) << 16;
    return v.f;
}
__device__ __forceinline__ void gload16(const void* g, void* l) {
    __builtin_amdgcn_global_load_lds(
        (const __attribute__((address_space(1))) unsigned int*)g,
        (__attribute__((address_space(3))) unsigned int*)l, 16, 0, 0);
}

// ---------------- fp32 -> bf16: x + Wq + Wk + Wv + Wo, 32 B/thread ----------------
__global__ __launch_bounds__(256)
void convert_all(const float* __restrict__ x,  const float* __restrict__ Wq,
                 const float* __restrict__ Wk, const float* __restrict__ Wv,
                 const float* __restrict__ Wo,
                 unsigned short* __restrict__ Xb, unsigned short* __restrict__ Wqkvb,
                 unsigned short* __restrict__ Wob)
{
    int i = blockIdx.x * 256 + threadIdx.x;          // 0 .. 1M-1, each 8 floats
    const float* src;
    unsigned short* dst;
    size_t off;
    if (i < (1 << 19)) {                             // x: 4M floats = 512K groups
        src = x; dst = Xb; off = (size_t)i;
    } else {
        int j = i - (1 << 19);
        int wsel = j >> 17;                          // 0..3
        off = (size_t)(j & ((1 << 17) - 1));
        src = (wsel == 0) ? Wq : (wsel == 1) ? Wk : (wsel == 2) ? Wv : Wo;
        dst = (wsel < 3) ? Wqkvb + (size_t)wsel * (1u << 20) : Wob;
    }
    float4 v0 = ((const float4*)src)[off * 2];
    float4 v1 = ((const float4*)src)[off * 2 + 1];
    u16x8 o = { f2bf(v0.x), f2bf(v0.y), f2bf(v0.z), f2bf(v0.w),
                f2bf(v1.x), f2bf(v1.y), f2bf(v1.z), f2bf(v1.w) };
    *(u16x8*)&dst[off * 8] = o;
}

// ---------------- RoPE in place on bf16 Q/K  [bh][s][64], 16 B/thread ----------------
__global__ __launch_bounds__(256)
void rope_bf16(unsigned short* __restrict__ Qb, unsigned short* __restrict__ Kb,
               const int* __restrict__ pos)
{
    int idx = blockIdx.x * 256 + threadIdx.x;    // 0..1M-1 (Q then K), each 8 bf16
    int tsel = idx >> 19;
    int i = idx & ((1 << 19) - 1);
    unsigned short* base = tsel ? Kb : Qb;
    int d8 = i & 7;
    int s  = (i >> 3) & (SEQ - 1);
    float P = (float)pos[s];
    const float NEG_L2 = -0.41524101186092103f;  // -log2(10000)/32

    u16x8 v = *(u16x8*)&base[(size_t)i * 8];
    u16x8 o;
    #pragma unroll
    for (int k = 0; k < 4; ++k) {
        int pi = d8 * 4 + k;
        float ang = P * exp2f((float)pi * NEG_L2);
        float sn, cs;
        sincosf(ang, &sn, &cs);
        float e0 = bf2f(v[2*k]), e1 = bf2f(v[2*k + 1]);
        o[2*k]     = f2bf(e0 * cs - e1 * sn);
        o[2*k + 1] = f2bf(e0 * sn + e1 * cs);
    }
    *(u16x8*)&base[(size_t)i * 8] = o;
}

// ---------------- MFMA GEMM (unchanged from R19) ----------------
template<int MODE>
__global__ __launch_bounds__(256)
void gemm_mfma(const unsigned short* __restrict__ A, const unsigned short* __restrict__ B,
               unsigned short* __restrict__ Qb, unsigned short* __restrict__ Kb,
               unsigned short* __restrict__ VTb, float* __restrict__ Cf)
{
    const int t = threadIdx.x;
    const int w = t >> 6, l = t & 63, lid = l & 15, hi = (l >> 4) * 16;
    const int wm = w >> 1, wn = w & 1;
    const int m0 = blockIdx.y * 128, n0 = blockIdx.x * 128;

    __shared__ __align__(16) char At[3][8192];
    __shared__ __align__(16) char Bt[3][8192];

    f32x4 acc[4][4];
    const f32x4 z4 = {0.f, 0.f, 0.f, 0.f};
    #pragma unroll
    for (int i = 0; i < 4; ++i)
        #pragma unroll
        for (int j = 0; j < 4; ++j) acc[i][j] = z4;

    const char* Ab = (const char*)A;
    const char* Bb = (const char*)B;

    auto stage = [&](int buf, int kt) {
        const int kbyte = kt * 64;
        #pragma unroll
        for (int i = 0; i < 2; ++i) {
            int o   = i * 4096 + t * 16;
            int row = o >> 6, cb = o & 63;
            int sw  = ((row >> 1) & 3) << 4;
            char* lbase_a = At[buf] + i * 4096 + (t >> 6) * 1024;
            char* lbase_b = Bt[buf] + i * 4096 + (t >> 6) * 1024;
            gload16(Ab + (size_t)(m0 + row) * 2048 + kbyte + (cb ^ sw), lbase_a);
            gload16(Bb + (size_t)(n0 + row) * 2048 + kbyte + (cb ^ sw), lbase_b);
        }
    };

    const int NKT = DM / 32;
    stage(0, 0);
    stage(1, 1);

    for (int kt = 0; kt < NKT; ++kt) {
        const int cur = kt % 3;
        if (kt == NKT - 1) asm volatile("s_waitcnt vmcnt(0)" ::: "memory");
        else               asm volatile("s_waitcnt vmcnt(4)" ::: "memory");
        __builtin_amdgcn_s_barrier();
        if (kt + 2 < NKT) stage((kt + 2) % 3, kt + 2);

        bf16x8 af[4], bfr[4];
        #pragma unroll
        for (int mf = 0; mf < 4; ++mf) {
            int ar = wm * 64 + mf * 16 + lid;
            af[mf] = *(const bf16x8*)(At[cur] + ar * 64 + (hi ^ (((ar >> 1) & 3) << 4)));
        }
        #pragma unroll
        for (int nf = 0; nf < 4; ++nf) {
            int br = wn * 64 + nf * 16 + lid;
            bfr[nf] = *(const bf16x8*)(Bt[cur] + br * 64 + (hi ^ (((br >> 1) & 3) << 4)));
        }
        __builtin_amdgcn_s_setprio(1);
        #pragma unroll
        for (int mf = 0; mf < 4; ++mf)
            #pragma unroll
            for (int nf = 0; nf < 4; ++nf)
                acc[mf][nf] = MFMA_B16(af[mf], bfr[nf], acc[mf][nf]);
        __builtin_amdgcn_s_setprio(0);
    }

    if (MODE == 1) {
        #pragma unroll
        for (int mf = 0; mf < 4; ++mf)
            #pragma unroll
            for (int nf = 0; nf < 4; ++nf) {
                int ncol = n0 + wn * 64 + nf * 16 + lid;
                #pragma unroll
                for (int jj = 0; jj < 4; ++jj) {
                    int mrow = m0 + wm * 64 + mf * 16 + (l >> 4) * 4 + jj;
                    Cf[(size_t)mrow * DM + ncol] = acc[mf][nf][jj];
                }
            }
    } else {
        const int z = n0 >> 10;                  // 0:Q 1:K 2:V
        const int nbase = n0 & 1023;
        #pragma unroll
        for (int mf = 0; mf < 4; ++mf)
            #pragma unroll
            for (int nf = 0; nf < 4; ++nf) {
                int ncol = nbase + wn * 64 + nf * 16 + lid;
                int h = ncol >> 6, d = ncol & 63;
                int mbase = m0 + wm * 64 + mf * 16 + (l >> 4) * 4;
                int b = mbase >> 11, s0v = mbase & 2047;
                if (z == 2) {
                    u16x4 pk = { f2bf(acc[mf][nf][0]), f2bf(acc[mf][nf][1]),
                                 f2bf(acc[mf][nf][2]), f2bf(acc[mf][nf][3]) };
                    *(u16x4*)&VTb[((size_t)(b * NH + h) * DKD + d) * SEQ + s0v] = pk;
                } else {
                    unsigned short* dst = (z == 0) ? Qb : Kb;
                    #pragma unroll
                    for (int jj = 0; jj < 4; ++jj)
                        dst[((size_t)(b * NH + h) * SEQ + (s0v + jj)) * DKD + d] =
                            f2bf(acc[mf][nf][jj]);
                }
            }
    }
}

// ---------------- MFMA flash attention: round-pipelined, register-P ----------------
// 512 thr: waves 0-3 = q-tile A, waves 4-7 = q-tile B = A+1 (same bh); K/V staged once.
// Software pipeline: round kt computes QK(kt) [MFMA] AND exp/PV(kt-1) [VALU+MFMA] --
// independent, so the exp chain hides under QK's MFMAs (previously serial: the two
// pipes alternated, MfmaUtil 17 / VALUBusy 25).
// P lives in REGISTERS (R13's shfl assembly, correctness HW-validated by R13's pass);
// its bpermutes now overlap QK instead of sitting on the serial path.
// K/V 4-deep: round kt stages K(kt+3), V(kt+2); steady-state s_waitcnt vmcnt(4)
// retires exactly K(kt) + V(kt-1). Slot audit: K write (kt+3)&3 == (kt-1)&3 (read at
// kt-1, pre-barrier); V write (kt+2)&3 == (kt-2)&3 (read at kt-1) -- no conflicts.
// Fixed-shift softmax: P = exp2(fma(s, log2e/8, -12*log2e)); denom via ones-MFMA.
__global__ __launch_bounds__(512)
void flash_mfma(const unsigned short* __restrict__ Qb, const unsigned short* __restrict__ Kb,
                const unsigned short* __restrict__ VTb, unsigned short* __restrict__ AOb)
{
    const int L  = blockIdx.y * 16 + blockIdx.x;     // 0..511
    const int g  = L >> 8, c = L & 255;
    const int j  = c & 15;
    const int bh = (g << 4) | (c >> 4);
    const int b = bh >> 4, h = bh & 15;
    const int qbA = g ? (30 - 2 * j) : (2 * j);
    const int qbB = qbA + 1;

    const int t = threadIdx.x;
    const int w8 = t >> 6, l = t & 63, lid = l & 15, hi = (l >> 4) * 16;
    const int h4 = l >> 4;
    const int tile = w8 >> 2, wq = w8 & 3;
    const int qbMy = tile ? qbB : qbA;
    const int ntMy = qbMy + 1;
    const int q0My = qbMy * 64;
    const int ntB  = qbB + 1;                        // loop bound (B = A+1), >= 2

    __shared__ __align__(16) char Kt[4][8192];
    __shared__ __align__(16) char Vt[4][8192];

    const char* Kbh = (const char*)(Kb  + (size_t)bh * SEQ * DKD);
    const char* Vbh = (const char*)(VTb + (size_t)bh * SEQ * DKD);
    const char* Qbh = (const char*)(Qb  + (size_t)bh * SEQ * DKD);

    const f32x4 z4 = {0.f, 0.f, 0.f, 0.f};
    const int qrow = wq * 16 + lid;
    const float CLOG = 0.18033688011112042f;     // log2(e)/8
    const float NMC  = -17.312340490667560f;     // -12*log2(e)

    bf16x8 onesv;
    #pragma unroll
    for (int i = 0; i < 8; ++i) onesv[i] = (short)0x3F80;   // bf16 1.0

    bf16x8 qf[2];
    qf[0] = *(const bf16x8*)(Qbh + (size_t)(q0My + qrow) * 128 + 0  + hi);
    qf[1] = *(const bf16x8*)(Qbh + (size_t)(q0My + qrow) * 128 + 64 + hi);

    f32x4 o[4], o5, sfP[4];
    #pragma unroll
    for (int nf = 0; nf < 4; ++nf) { o[nf] = z4; sfP[nf] = z4; }
    o5 = z4;

    // per-thread staging: 1 gload16 for K, 1 for V, per tile
    auto stageK = [&](int kt) {
        int o_ = t * 16, row = o_ >> 7, cl = o_ & 127, sw = (row & 7) << 4;
        gload16(Kbh + (size_t)(kt * 64 + row) * 128 + (cl ^ sw), Kt[kt & 3] + w8 * 1024);
    };
    auto stageV = [&](int kt) {
        int o_ = t * 16, row = o_ >> 7, cl = o_ & 127, sw = (row & 7) << 4;
        gload16(Vbh + (size_t)row * (SEQ * 2) + kt * 128 + (cl ^ sw), Vt[kt & 3] + w8 * 1024);
    };

    // P-exchange source lanes (R13, HW-validated)
    const int sl0 = lid + ((h4 & 1) << 5);
    const int sl1 = sl0 + 16;
    const bool selhi = (h4 >= 2);

    // prologue issue order MUST match in-loop order for vmcnt counting:
    // K0 | K1, V0 | K2, V1   (virtual rounds -3,-2,-1 of [K(r+3), V(r+2)])
    stageK(0);
    stageK(1);
    stageV(0);
    if (ntB >= 3) stageK(2);
    stageV(1);

    for (int kt = 0; kt <= ntB; ++kt) {
        if (kt <= ntB - 4) asm volatile("s_waitcnt vmcnt(4)" ::: "memory");
        else               asm volatile("s_waitcnt vmcnt(0)" ::: "memory");
        __builtin_amdgcn_s_barrier();    // tile kt (K) and kt-1 (V) resident block-wide
        if (kt + 3 <= ntB - 1) stageK(kt + 3);
        if (kt + 2 <= ntB - 1) stageV(kt + 2);

        // ---- QK(kt): S^T = K Q^T ; lane holds S[key=nf*16+4*h4+jj][q=wq*16+lid] ----
        f32x4 sfN[4];
        const bool doQK = (kt < ntMy);
        if (doQK) {
            __builtin_amdgcn_s_setprio(1);
            #pragma unroll
            for (int nf = 0; nf < 4; ++nf) {
                f32x4 a = z4;
                #pragma unroll
                for (int ks = 0; ks < 2; ++ks) {
                    int r  = nf * 16 + lid;
                    int cb = ks * 64 + hi;
                    bf16x8 kfr = *(const bf16x8*)(Kt[kt & 3] + r * 128 + (cb ^ ((r & 7) << 4)));
                    a = MFMA_B16(kfr, qf[ks], a);          // swapped operands
                }
                sfN[nf] = a;
            }
            __builtin_amdgcn_s_setprio(0);
        }

        // ---- exp/PV for score round ktS = kt-1 (overlaps QK(kt)) ----
        if (kt >= 1 && (kt - 1) < ntMy) {
            const int ktS = kt - 1;

            if (ktS == qbMy) {                   // causal mask on the diagonal tile
                const int qloc = wq * 16 + lid;
                #pragma unroll
                for (int nf = 0; nf < 4; ++nf)
                    #pragma unroll
                    for (int jj = 0; jj < 4; ++jj) {
                        int keyloc = nf * 16 + h4 * 4 + jj;
                        if (keyloc > qloc) sfP[nf][jj] = -1e30f;
                    }
            }

            // fixed-shift exp -> packed bf16 P quads in registers
            uint2 pk[4];
            #pragma unroll
            for (int nf = 0; nf < 4; ++nf) {
                float p0, p1, p2, p3;
                asm("v_exp_f32 %0, %1" : "=v"(p0) : "v"(fmaf(sfP[nf][0], CLOG, NMC)));
                asm("v_exp_f32 %0, %1" : "=v"(p1) : "v"(fmaf(sfP[nf][1], CLOG, NMC)));
                asm("v_exp_f32 %0, %1" : "=v"(p2) : "v"(fmaf(sfP[nf][2], CLOG, NMC)));
                asm("v_exp_f32 %0, %1" : "=v"(p3) : "v"(fmaf(sfP[nf][3], CLOG, NMC)));
                unsigned plo, phi;
                asm("v_cvt_pk_bf16_f32 %0, %1, %2" : "=v"(plo) : "v"(p0), "v"(p1));
                asm("v_cvt_pk_bf16_f32 %0, %1, %2" : "=v"(phi) : "v"(p2), "v"(p3));
                pk[nf].x = plo; pk[nf].y = phi;
            }

            // O += P V ; denom += P * ones  (P assembled from registers via shfl)
            #pragma unroll
            for (int ks = 0; ks < 2; ++ks) {
                unsigned A0x = __shfl((int)pk[2*ks    ].x, sl0);
                unsigned A0y = __shfl((int)pk[2*ks    ].y, sl0);
                unsigned A1x = __shfl((int)pk[2*ks + 1].x, sl0);
                unsigned A1y = __shfl((int)pk[2*ks + 1].y, sl0);
                unsigned B0x = __shfl((int)pk[2*ks    ].x, sl1);
                unsigned B0y = __shfl((int)pk[2*ks    ].y, sl1);
                unsigned B1x = __shfl((int)pk[2*ks + 1].x, sl1);
                unsigned B1y = __shfl((int)pk[2*ks + 1].y, sl1);
                union { unsigned u[4]; bf16x8 v; } pa;
                pa.u[0] = selhi ? A1x : A0x;
                pa.u[1] = selhi ? A1y : A0y;
                pa.u[2] = selhi ? B1x : B0x;
                pa.u[3] = selhi ? B1y : B0y;

                int cb = ks * 64 + hi;
                __builtin_amdgcn_s_setprio(1);
                #pragma unroll
                for (int nf = 0; nf < 4; ++nf) {
                    int dr = nf * 16 + lid;
                    bf16x8 vb = *(const bf16x8*)(Vt[ktS & 3] + dr * 128 + (cb ^ ((dr & 7) << 4)));
                    o[nf] = MFMA_B16(pa.v, vb, o[nf]);
                }
                o5 = MFMA_B16(pa.v, onesv, o5);
                __builtin_amdgcn_s_setprio(0);
            }
        }

        if (doQK) {
            #pragma unroll
            for (int nf = 0; nf < 4; ++nf) sfP[nf] = sfN[nf];
        }
    }

    // ---- epilogue: AO bf16 [b*S+s][h*64+d]; denom is o5 (same row layout) ----
    float inv[4];
    #pragma unroll
    for (int jj = 0; jj < 4; ++jj) inv[jj] = 1.0f / o5[jj];
    #pragma unroll
    for (int nf = 0; nf < 4; ++nf)
        #pragma unroll
        for (int jj = 0; jj < 4; ++jj) {
            int srow = q0My + wq * 16 + h4 * 4 + jj;
            int col  = h * 64 + nf * 16 + lid;
            AOb[((size_t)b * SEQ + srow) * DM + col] = f2bf(o[nf][jj] * inv[jj]);
        }
}

// ---------------- launch ----------------
extern "C" void kernel_launch(void* const* d_in, const int* in_sizes, int n_in,
                              void* d_out, int out_size, void* d_ws, size_t ws_size,
                              hipStream_t stream)
{
    const float* x   = (const float*)d_in[0];
    const int*   pos = (const int*)  d_in[1];
    const float* Wq  = (const float*)d_in[2];
    const float* Wk  = (const float*)d_in[3];
    const float* Wv  = (const float*)d_in[4];
    const float* Wo  = (const float*)d_in[5];
    float* out = (float*)d_out;

    const size_t M1 = 1u << 20;                 // 1M elements
    unsigned short* ws  = (unsigned short*)d_ws;
    unsigned short* Xb    = ws;                 // 4M
    unsigned short* Wqkvb = ws + 4 * M1;        // 3M (Wq|Wk|Wv rows)
    unsigned short* Wob   = ws + 7 * M1;        // 1M
    unsigned short* Qbf   = ws + 8 * M1;        // 4M  [bh][s][64]
    unsigned short* Kbf   = ws + 12 * M1;       // 4M  [bh][s][64]
    unsigned short* VTb   = ws + 16 * M1;       // 4M  [bh][64][s]
    unsigned short* AOb   = ws + 20 * M1;       // 4M  [b*s][1024]

    convert_all<<<4096, 256, 0, stream>>>(x, Wq, Wk, Wv, Wo, Xb, Wqkvb, Wob);

    // QKV projection (epilogue scatters Q,K row-major; V transposed)
    gemm_mfma<0><<<dim3(24, 32), 256, 0, stream>>>(Xb, Wqkvb, Qbf, Kbf, VTb, nullptr);

    // RoPE in place on bf16 Q/K (standalone — fusing into the GEMM epilogue
    // spilled the accumulator to scratch: R11, 270 us + 1.6 GB writes)
    rope_bf16<<<4096, 256, 0, stream>>>(Qbf, Kbf, pos);

    // flash attention (8-wave blocks, round-pipelined, register-P, 4-deep K/V)
    flash_mfma<<<dim3(16, 32), 512, 0, stream>>>(Qbf, Kbf, VTb, AOb);

    // output projection
    gemm_mfma<1><<<dim3(8, 32), 256, 0, stream>>>(AOb, Wob, nullptr, nullptr, nullptr, out);
}

// Round 22
// 121.095 us; speedup vs baseline: 1.0692x; 1.0692x over previous
//
#include <hip/hip_runtime.h>
#include <math.h>

#define SEQ   2048
#define BATCH 2
#define NH    16
#define DKD   64
#define DM    1024
#define MTOT  (BATCH*SEQ)   // 4096

typedef short bf16x8 __attribute__((ext_vector_type(8)));      // 8 bf16 (4 VGPR)
typedef float f32x4  __attribute__((ext_vector_type(4)));      // MFMA C/D
typedef unsigned short u16x4 __attribute__((ext_vector_type(4)));
typedef unsigned short u16x8 __attribute__((ext_vector_type(8)));

#define MFMA_B16(a,b,c) __builtin_amdgcn_mfma_f32_16x16x32_bf16((a),(b),(c),0,0,0)

__device__ __forceinline__ unsigned short f2bf(float f) {
    union { float f; unsigned int u; } v; v.f = f;
    unsigned int r = v.u + 0x7FFFu + ((v.u >> 16) & 1u);   // RNE
    return (unsigned short)(r >> 16);
}
__device__ __forceinline__ float bf2f(unsigned short h) {
    union { unsigned int u; float f; } v; v.u = ((unsigned int)h) << 16;
    return v.f;
}
__device__ __forceinline__ void gload16(const void* g, void* l) {
    __builtin_amdgcn_global_load_lds(
        (const __attribute__((address_space(1))) unsigned int*)g,
        (__attribute__((address_space(3))) unsigned int*)l, 16, 0, 0);
}

// ---------------- fp32 -> bf16: x + Wq + Wk + Wv + Wo, 32 B/thread ----------------
__global__ __launch_bounds__(256)
void convert_all(const float* __restrict__ x,  const float* __restrict__ Wq,
                 const float* __restrict__ Wk, const float* __restrict__ Wv,
                 const float* __restrict__ Wo,
                 unsigned short* __restrict__ Xb, unsigned short* __restrict__ Wqkvb,
                 unsigned short* __restrict__ Wob)
{
    int i = blockIdx.x * 256 + threadIdx.x;          // 0 .. 1M-1, each 8 floats
    const float* src;
    unsigned short* dst;
    size_t off;
    if (i < (1 << 19)) {                             // x: 4M floats = 512K groups
        src = x; dst = Xb; off = (size_t)i;
    } else {
        int j = i - (1 << 19);
        int wsel = j >> 17;                          // 0..3
        off = (size_t)(j & ((1 << 17) - 1));
        src = (wsel == 0) ? Wq : (wsel == 1) ? Wk : (wsel == 2) ? Wv : Wo;
        dst = (wsel < 3) ? Wqkvb + (size_t)wsel * (1u << 20) : Wob;
    }
    float4 v0 = ((const float4*)src)[off * 2];
    float4 v1 = ((const float4*)src)[off * 2 + 1];
    u16x8 o = { f2bf(v0.x), f2bf(v0.y), f2bf(v0.z), f2bf(v0.w),
                f2bf(v1.x), f2bf(v1.y), f2bf(v1.z), f2bf(v1.w) };
    *(u16x8*)&dst[off * 8] = o;
}

// ---------------- RoPE in place on bf16 Q/K  [bh][s][64], 16 B/thread ----------------
__global__ __launch_bounds__(256)
void rope_bf16(unsigned short* __restrict__ Qb, unsigned short* __restrict__ Kb,
               const int* __restrict__ pos)
{
    int idx = blockIdx.x * 256 + threadIdx.x;    // 0..1M-1 (Q then K), each 8 bf16
    int tsel = idx >> 19;
    int i = idx & ((1 << 19) - 1);
    unsigned short* base = tsel ? Kb : Qb;
    int d8 = i & 7;
    int s  = (i >> 3) & (SEQ - 1);
    float P = (float)pos[s];
    const float NEG_L2 = -0.41524101186092103f;  // -log2(10000)/32

    u16x8 v = *(u16x8*)&base[(size_t)i * 8];
    u16x8 o;
    #pragma unroll
    for (int k = 0; k < 4; ++k) {
        int pi = d8 * 4 + k;
        float ang = P * exp2f((float)pi * NEG_L2);
        float sn, cs;
        sincosf(ang, &sn, &cs);
        float e0 = bf2f(v[2*k]), e1 = bf2f(v[2*k + 1]);
        o[2*k]     = f2bf(e0 * cs - e1 * sn);
        o[2*k + 1] = f2bf(e0 * sn + e1 * cs);
    }
    *(u16x8*)&base[(size_t)i * 8] = o;
}

// ---------------- MFMA GEMM: BK=64, 2-deep stage-ahead pipeline ----------------
// C[M][N] = A[M][K] x B[N][K]^T, bf16 in / f32 acc; 128x128 tile, BK=64, 4 waves.
// 16 rounds (was 32): per-round fixed cost (barrier, waitcnt) amortized 2x.
// LDS rows are 128 B -> unswizzled reads would be 16-way conflicted; XOR-swizzle
// byte ^= ((row&7)<<4) (rule #21: linear gload dest, pre-swizzled global source,
// same XOR on frag reads) -> 2-way (free). Stage(kt+1) is issued right after the
// barrier; vmcnt(0) at next round's top hits loads that had a full round to land.
// MODE 0: N=3072, epilogue scatters Q,K ([bh][s][d]) and V transposed ([bh][d][s])
// MODE 1: N=1024, epilogue writes fp32 row-major C
template<int MODE>
__global__ __launch_bounds__(256)
void gemm_mfma(const unsigned short* __restrict__ A, const unsigned short* __restrict__ B,
               unsigned short* __restrict__ Qb, unsigned short* __restrict__ Kb,
               unsigned short* __restrict__ VTb, float* __restrict__ Cf)
{
    const int t = threadIdx.x;
    const int w = t >> 6, l = t & 63, lid = l & 15, hi = (l >> 4) * 16;
    const int wm = w >> 1, wn = w & 1;
    const int m0 = blockIdx.y * 128, n0 = blockIdx.x * 128;

    __shared__ __align__(16) char At[2][16384];   // [128 rows][64 k] bf16, 128 B rows
    __shared__ __align__(16) char Bt[2][16384];

    f32x4 acc[4][4];
    const f32x4 z4 = {0.f, 0.f, 0.f, 0.f};
    #pragma unroll
    for (int i = 0; i < 4; ++i)
        #pragma unroll
        for (int j = 0; j < 4; ++j) acc[i][j] = z4;

    const char* Ab = (const char*)A;
    const char* Bb = (const char*)B;

    auto stage = [&](int buf, int kt) {           // 8 gload16 per thread
        const int kbyte = kt * 128;               // K-tile of 64 bf16
        #pragma unroll
        for (int i = 0; i < 4; ++i) {
            int o   = i * 4096 + t * 16;
            int row = o >> 7, cl = o & 127;
            int sw  = (row & 7) << 4;
            char* la = At[buf] + i * 4096 + w * 1024;
            char* lb = Bt[buf] + i * 4096 + w * 1024;
            gload16(Ab + (size_t)(m0 + row) * 2048 + kbyte + (cl ^ sw), la);
            gload16(Bb + (size_t)(n0 + row) * 2048 + kbyte + (cl ^ sw), lb);
        }
    };

    const int NKT = DM / 64;                      // 16
    stage(0, 0);

    for (int kt = 0; kt < NKT; ++kt) {
        const int cur = kt & 1;
        asm volatile("s_waitcnt vmcnt(0)" ::: "memory");  // tile kt (issued last round)
        __builtin_amdgcn_s_barrier();                     // resident block-wide;
                                                          // buf[cur^1] free of readers
        if (kt + 1 < NKT) stage(cur ^ 1, kt + 1);

        #pragma unroll
        for (int ks2 = 0; ks2 < 2; ++ks2) {
            bf16x8 af[4], bfr[4];
            #pragma unroll
            for (int mf = 0; mf < 4; ++mf) {
                int ar = wm * 64 + mf * 16 + lid;
                af[mf] = *(const bf16x8*)(At[cur] + ar * 128 +
                                          ((ks2 * 64 + hi) ^ ((ar & 7) << 4)));
            }
            #pragma unroll
            for (int nf = 0; nf < 4; ++nf) {
                int br = wn * 64 + nf * 16 + lid;
                bfr[nf] = *(const bf16x8*)(Bt[cur] + br * 128 +
                                           ((ks2 * 64 + hi) ^ ((br & 7) << 4)));
            }
            __builtin_amdgcn_s_setprio(1);
            #pragma unroll
            for (int mf = 0; mf < 4; ++mf)
                #pragma unroll
                for (int nf = 0; nf < 4; ++nf)
                    acc[mf][nf] = MFMA_B16(af[mf], bfr[nf], acc[mf][nf]);
            __builtin_amdgcn_s_setprio(0);
        }
    }

    if (MODE == 1) {
        #pragma unroll
        for (int mf = 0; mf < 4; ++mf)
            #pragma unroll
            for (int nf = 0; nf < 4; ++nf) {
                int ncol = n0 + wn * 64 + nf * 16 + lid;
                #pragma unroll
                for (int jj = 0; jj < 4; ++jj) {
                    int mrow = m0 + wm * 64 + mf * 16 + (l >> 4) * 4 + jj;
                    Cf[(size_t)mrow * DM + ncol] = acc[mf][nf][jj];
                }
            }
    } else {
        const int z = n0 >> 10;                  // 0:Q 1:K 2:V
        const int nbase = n0 & 1023;
        #pragma unroll
        for (int mf = 0; mf < 4; ++mf)
            #pragma unroll
            for (int nf = 0; nf < 4; ++nf) {
                int ncol = nbase + wn * 64 + nf * 16 + lid;
                int h = ncol >> 6, d = ncol & 63;
                int mbase = m0 + wm * 64 + mf * 16 + (l >> 4) * 4;
                int b = mbase >> 11, s0v = mbase & 2047;
                if (z == 2) {
                    u16x4 pk = { f2bf(acc[mf][nf][0]), f2bf(acc[mf][nf][1]),
                                 f2bf(acc[mf][nf][2]), f2bf(acc[mf][nf][3]) };
                    *(u16x4*)&VTb[((size_t)(b * NH + h) * DKD + d) * SEQ + s0v] = pk;
                } else {
                    unsigned short* dst = (z == 0) ? Qb : Kb;
                    #pragma unroll
                    for (int jj = 0; jj < 4; ++jj)
                        dst[((size_t)(b * NH + h) * SEQ + (s0v + jj)) * DKD + d] =
                            f2bf(acc[mf][nf][jj]);
                }
            }
    }
}

// ---------------- MFMA flash attention: counted-vmcnt pipeline (exact R18) ----------
// 512 thr: waves 0-3 = q-tile A, waves 4-7 = q-tile B = A+1 (same bh); K/V staged once.
// 3-deep K/V buffers; per round: s_waitcnt vmcnt(2) -> s_barrier -> stage(kt+2) ->
// compute. P through LDS (register-P via shfl regressed twice: bpermute contends on
// the same LDS port as the QK/PV ds_reads -- R13, R20).
// Fixed-shift softmax: P = exp2(fma(s, log2e/8, -12*log2e)); denom via ones-MFMA.
__global__ __launch_bounds__(512)
void flash_mfma(const unsigned short* __restrict__ Qb, const unsigned short* __restrict__ Kb,
                const unsigned short* __restrict__ VTb, unsigned short* __restrict__ AOb)
{
    const int L  = blockIdx.y * 16 + blockIdx.x;     // 0..511
    const int g  = L >> 8, c = L & 255;
    const int j  = c & 15;
    const int bh = (g << 4) | (c >> 4);
    const int b = bh >> 4, h = bh & 15;
    const int qbA = g ? (30 - 2 * j) : (2 * j);
    const int qbB = qbA + 1;

    const int t = threadIdx.x;
    const int w8 = t >> 6, l = t & 63, lid = l & 15, hi = (l >> 4) * 16;
    const int h4 = l >> 4;
    const int tile = w8 >> 2, wq = w8 & 3;
    const int qbMy = tile ? qbB : qbA;
    const int ntMy = qbMy + 1;
    const int q0My = qbMy * 64;
    const int ntB  = qbB + 1;                        // loop bound (B = A+1), >= 2

    __shared__ __align__(16) char Kt[3][8192];
    __shared__ __align__(16) char Vt[3][8192];
    __shared__ __align__(16) char Pt[2][8192];       // per-tile P

    const char* Kbh = (const char*)(Kb  + (size_t)bh * SEQ * DKD);
    const char* Vbh = (const char*)(VTb + (size_t)bh * SEQ * DKD);
    const char* Qbh = (const char*)(Qb  + (size_t)bh * SEQ * DKD);

    const f32x4 z4 = {0.f, 0.f, 0.f, 0.f};
    const int qrow = wq * 16 + lid;
    const float CLOG = 0.18033688011112042f;     // log2(e)/8
    const float NMC  = -17.312340490667560f;     // -12*log2(e)

    bf16x8 onesv;
    #pragma unroll
    for (int i = 0; i < 8; ++i) onesv[i] = (short)0x3F80;   // bf16 1.0

    bf16x8 qf[2];
    qf[0] = *(const bf16x8*)(Qbh + (size_t)(q0My + qrow) * 128 + 0  + hi);
    qf[1] = *(const bf16x8*)(Qbh + (size_t)(q0My + qrow) * 128 + 64 + hi);

    f32x4 o[4], o5;
    #pragma unroll
    for (int nf = 0; nf < 4; ++nf) o[nf] = z4;
    o5 = z4;

    auto stage = [&](int buf, int kt) {
        const int k0 = kt * 64;
        int o_  = t * 16;
        int row = o_ >> 7, cl = o_ & 127;
        int sw  = (row & 7) << 4;
        char* lK = Kt[buf] + w8 * 1024;
        char* lV = Vt[buf] + w8 * 1024;
        gload16(Kbh + (size_t)(k0 + row) * 128 + (cl ^ sw), lK);
        gload16(Vbh + (size_t)row * (SEQ * 2) + k0 * 2 + (cl ^ sw), lV);
    };

    stage(0, 0);
    stage(1, 1);

    for (int kt = 0; kt < ntB; ++kt) {
        const int cur = kt % 3;

        if (kt == ntB - 1) asm volatile("s_waitcnt vmcnt(0)" ::: "memory");
        else               asm volatile("s_waitcnt vmcnt(2)" ::: "memory");
        __builtin_amdgcn_s_barrier();
        if (kt + 2 < ntB) stage((kt + 2) % 3, kt + 2);

        if (kt < ntMy) {
            // ---- S^T = K Q^T ----
            f32x4 sf[4];
            __builtin_amdgcn_s_setprio(1);
            #pragma unroll
            for (int nf = 0; nf < 4; ++nf) {
                f32x4 a = z4;
                #pragma unroll
                for (int ks = 0; ks < 2; ++ks) {
                    int r  = nf * 16 + lid;
                    int cb = ks * 64 + hi;
                    bf16x8 kfr = *(const bf16x8*)(Kt[cur] + r * 128 + (cb ^ ((r & 7) << 4)));
                    a = MFMA_B16(kfr, qf[ks], a);          // swapped operands
                }
                sf[nf] = a;
            }
            __builtin_amdgcn_s_setprio(0);

            // ---- causal mask on the diagonal tile ----
            if (kt == qbMy) {
                const int qloc = wq * 16 + lid;
                #pragma unroll
                for (int nf = 0; nf < 4; ++nf) {
                    #pragma unroll
                    for (int jj = 0; jj < 4; ++jj) {
                        int keyloc = nf * 16 + h4 * 4 + jj;
                        if (keyloc > qloc) sf[nf][jj] = -1e30f;
                    }
                }
            }

            // ---- fixed-shift exp ----
            uint2 pk[4];
            #pragma unroll
            for (int nf = 0; nf < 4; ++nf) {
                float p0, p1, p2, p3;
                asm("v_exp_f32 %0, %1" : "=v"(p0) : "v"(fmaf(sf[nf][0], CLOG, NMC)));
                asm("v_exp_f32 %0, %1" : "=v"(p1) : "v"(fmaf(sf[nf][1], CLOG, NMC)));
                asm("v_exp_f32 %0, %1" : "=v"(p2) : "v"(fmaf(sf[nf][2], CLOG, NMC)));
                asm("v_exp_f32 %0, %1" : "=v"(p3) : "v"(fmaf(sf[nf][3], CLOG, NMC)));
                unsigned plo, phi;
                asm("v_cvt_pk_bf16_f32 %0, %1, %2" : "=v"(plo) : "v"(p0), "v"(p1));
                asm("v_cvt_pk_bf16_f32 %0, %1, %2" : "=v"(phi) : "v"(p2), "v"(p3));
                pk[nf].x = plo; pk[nf].y = phi;
            }

            // ---- write P row-chunk ----
            {
                const int rowq = wq * 16 + lid;
                const int swz  = (lid & 7) << 4;
                char* base = Pt[tile] + rowq * 128;
                #pragma unroll
                for (int nf = 0; nf < 4; ++nf)
                    *(uint2*)(base + ((nf * 32 + 8 * h4) ^ swz)) = pk[nf];
            }

            // ---- O += P V ; denom += P * ones ----
            #pragma unroll
            for (int ks = 0; ks < 2; ++ks) {
                int cb = ks * 64 + hi;
                int qr = wq * 16 + lid;
                bf16x8 pa = *(const bf16x8*)(Pt[tile] + qr * 128 + (cb ^ ((qr & 7) << 4)));
                __builtin_amdgcn_s_setprio(1);
                #pragma unroll
                for (int nf = 0; nf < 4; ++nf) {
                    int dr = nf * 16 + lid;
                    bf16x8 vb = *(const bf16x8*)(Vt[cur] + dr * 128 + (cb ^ ((dr & 7) << 4)));
                    o[nf] = MFMA_B16(pa, vb, o[nf]);
                }
                o5 = MFMA_B16(pa, onesv, o5);
                __builtin_amdgcn_s_setprio(0);
            }
        }
    }

    // ---- epilogue ----
    float inv[4];
    #pragma unroll
    for (int jj = 0; jj < 4; ++jj) inv[jj] = 1.0f / o5[jj];
    #pragma unroll
    for (int nf = 0; nf < 4; ++nf)
        #pragma unroll
        for (int jj = 0; jj < 4; ++jj) {
            int srow = q0My + wq * 16 + h4 * 4 + jj;
            int col  = h * 64 + nf * 16 + lid;
            AOb[((size_t)b * SEQ + srow) * DM + col] = f2bf(o[nf][jj] * inv[jj]);
        }
}

// ---------------- launch ----------------
extern "C" void kernel_launch(void* const* d_in, const int* in_sizes, int n_in,
                              void* d_out, int out_size, void* d_ws, size_t ws_size,
                              hipStream_t stream)
{
    const float* x   = (const float*)d_in[0];
    const int*   pos = (const int*)  d_in[1];
    const float* Wq  = (const float*)d_in[2];
    const float* Wk  = (const float*)d_in[3];
    const float* Wv  = (const float*)d_in[4];
    const float* Wo  = (const float*)d_in[5];
    float* out = (float*)d_out;

    const size_t M1 = 1u << 20;                 // 1M elements
    unsigned short* ws  = (unsigned short*)d_ws;
    unsigned short* Xb    = ws;                 // 4M
    unsigned short* Wqkvb = ws + 4 * M1;        // 3M (Wq|Wk|Wv rows)
    unsigned short* Wob   = ws + 7 * M1;        // 1M
    unsigned short* Qbf   = ws + 8 * M1;        // 4M  [bh][s][64]
    unsigned short* Kbf   = ws + 12 * M1;       // 4M  [bh][s][64]
    unsigned short* VTb   = ws + 16 * M1;       // 4M  [bh][64][s]
    unsigned short* AOb   = ws + 20 * M1;       // 4M  [b*s][1024]

    convert_all<<<4096, 256, 0, stream>>>(x, Wq, Wk, Wv, Wo, Xb, Wqkvb, Wob);

    // QKV projection (epilogue scatters Q,K row-major; V transposed)
    gemm_mfma<0><<<dim3(24, 32), 256, 0, stream>>>(Xb, Wqkvb, Qbf, Kbf, VTb, nullptr);

    // RoPE in place on bf16 Q/K (standalone — fusing into the GEMM epilogue
    // spilled the accumulator to scratch: R11, 270 us + 1.6 GB writes)
    rope_bf16<<<4096, 256, 0, stream>>>(Qbf, Kbf, pos);

    // flash attention (8-wave blocks, counted-vmcnt 3-deep pipeline, R18)
    flash_mfma<<<dim3(16, 32), 512, 0, stream>>>(Qbf, Kbf, VTb, AOb);

    // output projection
    gemm_mfma<1><<<dim3(8, 32), 256, 0, stream>>>(AOb, Wob, nullptr, nullptr, nullptr, out);
}

// Round 23
// 119.534 us; speedup vs baseline: 1.0831x; 1.0131x over previous
//
#include <hip/hip_runtime.h>
#include <math.h>

#define SEQ   2048
#define BATCH 2
#define NH    16
#define DKD   64
#define DM    1024
#define MTOT  (BATCH*SEQ)   // 4096

typedef short bf16x8 __attribute__((ext_vector_type(8)));      // 8 bf16 (4 VGPR)
typedef float f32x4  __attribute__((ext_vector_type(4)));      // MFMA C/D
typedef unsigned short u16x4 __attribute__((ext_vector_type(4)));
typedef unsigned short u16x8 __attribute__((ext_vector_type(8)));

#define MFMA_B16(a,b,c) __builtin_amdgcn_mfma_f32_16x16x32_bf16((a),(b),(c),0,0,0)

__device__ __forceinline__ unsigned short f2bf(float f) {
    union { float f; unsigned int u; } v; v.f = f;
    unsigned int r = v.u + 0x7FFFu + ((v.u >> 16) & 1u);   // RNE
    return (unsigned short)(r >> 16);
}
__device__ __forceinline__ float bf2f(unsigned short h) {
    union { unsigned int u; float f; } v; v.u = ((unsigned int)h) << 16;
    return v.f;
}
__device__ __forceinline__ void gload16(const void* g, void* l) {
    __builtin_amdgcn_global_load_lds(
        (const __attribute__((address_space(1))) unsigned int*)g,
        (__attribute__((address_space(3))) unsigned int*)l, 16, 0, 0);
}

// ---------------- fp32 -> bf16: x + Wq + Wk + Wv + Wo, 32 B/thread ----------------
__global__ __launch_bounds__(256)
void convert_all(const float* __restrict__ x,  const float* __restrict__ Wq,
                 const float* __restrict__ Wk, const float* __restrict__ Wv,
                 const float* __restrict__ Wo,
                 unsigned short* __restrict__ Xb, unsigned short* __restrict__ Wqkvb,
                 unsigned short* __restrict__ Wob)
{
    int i = blockIdx.x * 256 + threadIdx.x;          // 0 .. 1M-1, each 8 floats
    const float* src;
    unsigned short* dst;
    size_t off;
    if (i < (1 << 19)) {                             // x: 4M floats = 512K groups
        src = x; dst = Xb; off = (size_t)i;
    } else {
        int j = i - (1 << 19);
        int wsel = j >> 17;                          // 0..3
        off = (size_t)(j & ((1 << 17) - 1));
        src = (wsel == 0) ? Wq : (wsel == 1) ? Wk : (wsel == 2) ? Wv : Wo;
        dst = (wsel < 3) ? Wqkvb + (size_t)wsel * (1u << 20) : Wob;
    }
    float4 v0 = ((const float4*)src)[off * 2];
    float4 v1 = ((const float4*)src)[off * 2 + 1];
    u16x8 o = { f2bf(v0.x), f2bf(v0.y), f2bf(v0.z), f2bf(v0.w),
                f2bf(v1.x), f2bf(v1.y), f2bf(v1.z), f2bf(v1.w) };
    *(u16x8*)&dst[off * 8] = o;
}

// ---------------- RoPE in place on bf16 Q/K  [bh][s][64], 16 B/thread ----------------
__global__ __launch_bounds__(256)
void rope_bf16(unsigned short* __restrict__ Qb, unsigned short* __restrict__ Kb,
               const int* __restrict__ pos)
{
    int idx = blockIdx.x * 256 + threadIdx.x;    // 0..1M-1 (Q then K), each 8 bf16
    int tsel = idx >> 19;
    int i = idx & ((1 << 19) - 1);
    unsigned short* base = tsel ? Kb : Qb;
    int d8 = i & 7;
    int s  = (i >> 3) & (SEQ - 1);
    float P = (float)pos[s];
    const float NEG_L2 = -0.41524101186092103f;  // -log2(10000)/32

    u16x8 v = *(u16x8*)&base[(size_t)i * 8];
    u16x8 o;
    #pragma unroll
    for (int k = 0; k < 4; ++k) {
        int pi = d8 * 4 + k;
        float ang = P * exp2f((float)pi * NEG_L2);
        float sn, cs;
        sincosf(ang, &sn, &cs);
        float e0 = bf2f(v[2*k]), e1 = bf2f(v[2*k + 1]);
        o[2*k]     = f2bf(e0 * cs - e1 * sn);
        o[2*k + 1] = f2bf(e0 * sn + e1 * cs);
    }
    *(u16x8*)&base[(size_t)i * 8] = o;
}

// ---------------- MFMA GEMM: 3-deep counted-vmcnt pipeline + T2 read-swizzle -------
// (exact R19 kernel — measured 42.3 us, 0 bank conflicts, 3 blocks/CU.
//  BK=64 variant regressed to 46.5 us: occupancy 25->14% and per-round vmcnt(0)
//  full drain beat the halved round count. R22 lesson.)
template<int MODE>
__global__ __launch_bounds__(256)
void gemm_mfma(const unsigned short* __restrict__ A, const unsigned short* __restrict__ B,
               unsigned short* __restrict__ Qb, unsigned short* __restrict__ Kb,
               unsigned short* __restrict__ VTb, float* __restrict__ Cf)
{
    const int t = threadIdx.x;
    const int w = t >> 6, l = t & 63, lid = l & 15, hi = (l >> 4) * 16;
    const int wm = w >> 1, wn = w & 1;
    const int m0 = blockIdx.y * 128, n0 = blockIdx.x * 128;

    __shared__ __align__(16) char At[3][8192];   // [128 m][32 k] bf16, 64 B rows
    __shared__ __align__(16) char Bt[3][8192];

    f32x4 acc[4][4];
    const f32x4 z4 = {0.f, 0.f, 0.f, 0.f};
    #pragma unroll
    for (int i = 0; i < 4; ++i)
        #pragma unroll
        for (int j = 0; j < 4; ++j) acc[i][j] = z4;

    const char* Ab = (const char*)A;
    const char* Bb = (const char*)B;

    auto stage = [&](int buf, int kt) {          // 4 gload16 per thread
        const int kbyte = kt * 64;
        #pragma unroll
        for (int i = 0; i < 2; ++i) {
            int o   = i * 4096 + t * 16;
            int row = o >> 6, cb = o & 63;
            int sw  = ((row >> 1) & 3) << 4;     // T2: pre-swizzle global source
            char* lbase_a = At[buf] + i * 4096 + (t >> 6) * 1024;
            char* lbase_b = Bt[buf] + i * 4096 + (t >> 6) * 1024;
            gload16(Ab + (size_t)(m0 + row) * 2048 + kbyte + (cb ^ sw), lbase_a);
            gload16(Bb + (size_t)(n0 + row) * 2048 + kbyte + (cb ^ sw), lbase_b);
        }
    };

    const int NKT = DM / 32;                     // 32
    stage(0, 0);
    stage(1, 1);

    for (int kt = 0; kt < NKT; ++kt) {
        const int cur = kt % 3;
        if (kt == NKT - 1) asm volatile("s_waitcnt vmcnt(0)" ::: "memory");
        else               asm volatile("s_waitcnt vmcnt(4)" ::: "memory");
        __builtin_amdgcn_s_barrier();            // tile kt resident block-wide;
                                                 // buf[(kt+2)%3] free of readers
        if (kt + 2 < NKT) stage((kt + 2) % 3, kt + 2);

        bf16x8 af[4], bfr[4];
        #pragma unroll
        for (int mf = 0; mf < 4; ++mf) {
            int ar = wm * 64 + mf * 16 + lid;
            af[mf] = *(const bf16x8*)(At[cur] + ar * 64 + (hi ^ (((ar >> 1) & 3) << 4)));
        }
        #pragma unroll
        for (int nf = 0; nf < 4; ++nf) {
            int br = wn * 64 + nf * 16 + lid;
            bfr[nf] = *(const bf16x8*)(Bt[cur] + br * 64 + (hi ^ (((br >> 1) & 3) << 4)));
        }
        __builtin_amdgcn_s_setprio(1);
        #pragma unroll
        for (int mf = 0; mf < 4; ++mf)
            #pragma unroll
            for (int nf = 0; nf < 4; ++nf)
                acc[mf][nf] = MFMA_B16(af[mf], bfr[nf], acc[mf][nf]);
        __builtin_amdgcn_s_setprio(0);
    }

    if (MODE == 1) {
        #pragma unroll
        for (int mf = 0; mf < 4; ++mf)
            #pragma unroll
            for (int nf = 0; nf < 4; ++nf) {
                int ncol = n0 + wn * 64 + nf * 16 + lid;
                #pragma unroll
                for (int jj = 0; jj < 4; ++jj) {
                    int mrow = m0 + wm * 64 + mf * 16 + (l >> 4) * 4 + jj;
                    Cf[(size_t)mrow * DM + ncol] = acc[mf][nf][jj];
                }
            }
    } else {
        const int z = n0 >> 10;                  // 0:Q 1:K 2:V
        const int nbase = n0 & 1023;
        #pragma unroll
        for (int mf = 0; mf < 4; ++mf)
            #pragma unroll
            for (int nf = 0; nf < 4; ++nf) {
                int ncol = nbase + wn * 64 + nf * 16 + lid;
                int h = ncol >> 6, d = ncol & 63;
                int mbase = m0 + wm * 64 + mf * 16 + (l >> 4) * 4;
                int b = mbase >> 11, s0v = mbase & 2047;
                if (z == 2) {
                    u16x4 pk = { f2bf(acc[mf][nf][0]), f2bf(acc[mf][nf][1]),
                                 f2bf(acc[mf][nf][2]), f2bf(acc[mf][nf][3]) };
                    *(u16x4*)&VTb[((size_t)(b * NH + h) * DKD + d) * SEQ + s0v] = pk;
                } else {
                    unsigned short* dst = (z == 0) ? Qb : Kb;
                    #pragma unroll
                    for (int jj = 0; jj < 4; ++jj)
                        dst[((size_t)(b * NH + h) * SEQ + (s0v + jj)) * DKD + d] =
                            f2bf(acc[mf][nf][jj]);
                }
            }
    }
}

// ---------------- MFMA flash attention: counted-vmcnt pipeline (exact R18) ----------
// 512 thr: waves 0-3 = q-tile A, waves 4-7 = q-tile B = A+1 (same bh); K/V staged once.
// 3-deep K/V buffers; per round: s_waitcnt vmcnt(2) -> s_barrier -> stage(kt+2) ->
// compute. P through LDS (register-P via shfl regressed twice: bpermute contends on
// the same LDS port as the QK/PV ds_reads -- R13, R20).
// Fixed-shift softmax: P = exp2(fma(s, log2e/8, -12*log2e)); denom via ones-MFMA.
__global__ __launch_bounds__(512)
void flash_mfma(const unsigned short* __restrict__ Qb, const unsigned short* __restrict__ Kb,
                const unsigned short* __restrict__ VTb, unsigned short* __restrict__ AOb)
{
    const int L  = blockIdx.y * 16 + blockIdx.x;     // 0..511
    const int g  = L >> 8, c = L & 255;
    const int j  = c & 15;
    const int bh = (g << 4) | (c >> 4);
    const int b = bh >> 4, h = bh & 15;
    const int qbA = g ? (30 - 2 * j) : (2 * j);
    const int qbB = qbA + 1;

    const int t = threadIdx.x;
    const int w8 = t >> 6, l = t & 63, lid = l & 15, hi = (l >> 4) * 16;
    const int h4 = l >> 4;
    const int tile = w8 >> 2, wq = w8 & 3;
    const int qbMy = tile ? qbB : qbA;
    const int ntMy = qbMy + 1;
    const int q0My = qbMy * 64;
    const int ntB  = qbB + 1;                        // loop bound (B = A+1), >= 2

    __shared__ __align__(16) char Kt[3][8192];
    __shared__ __align__(16) char Vt[3][8192];
    __shared__ __align__(16) char Pt[2][8192];       // per-tile P

    const char* Kbh = (const char*)(Kb  + (size_t)bh * SEQ * DKD);
    const char* Vbh = (const char*)(VTb + (size_t)bh * SEQ * DKD);
    const char* Qbh = (const char*)(Qb  + (size_t)bh * SEQ * DKD);

    const f32x4 z4 = {0.f, 0.f, 0.f, 0.f};
    const int qrow = wq * 16 + lid;
    const float CLOG = 0.18033688011112042f;     // log2(e)/8
    const float NMC  = -17.312340490667560f;     // -12*log2(e)

    bf16x8 onesv;
    #pragma unroll
    for (int i = 0; i < 8; ++i) onesv[i] = (short)0x3F80;   // bf16 1.0

    bf16x8 qf[2];
    qf[0] = *(const bf16x8*)(Qbh + (size_t)(q0My + qrow) * 128 + 0  + hi);
    qf[1] = *(const bf16x8*)(Qbh + (size_t)(q0My + qrow) * 128 + 64 + hi);

    f32x4 o[4], o5;
    #pragma unroll
    for (int nf = 0; nf < 4; ++nf) o[nf] = z4;
    o5 = z4;

    auto stage = [&](int buf, int kt) {
        const int k0 = kt * 64;
        int o_  = t * 16;
        int row = o_ >> 7, cl = o_ & 127;
        int sw  = (row & 7) << 4;
        char* lK = Kt[buf] + w8 * 1024;
        char* lV = Vt[buf] + w8 * 1024;
        gload16(Kbh + (size_t)(k0 + row) * 128 + (cl ^ sw), lK);
        gload16(Vbh + (size_t)row * (SEQ * 2) + k0 * 2 + (cl ^ sw), lV);
    };

    stage(0, 0);
    stage(1, 1);

    for (int kt = 0; kt < ntB; ++kt) {
        const int cur = kt % 3;

        if (kt == ntB - 1) asm volatile("s_waitcnt vmcnt(0)" ::: "memory");
        else               asm volatile("s_waitcnt vmcnt(2)" ::: "memory");
        __builtin_amdgcn_s_barrier();
        if (kt + 2 < ntB) stage((kt + 2) % 3, kt + 2);

        if (kt < ntMy) {
            // ---- S^T = K Q^T ----
            f32x4 sf[4];
            __builtin_amdgcn_s_setprio(1);
            #pragma unroll
            for (int nf = 0; nf < 4; ++nf) {
                f32x4 a = z4;
                #pragma unroll
                for (int ks = 0; ks < 2; ++ks) {
                    int r  = nf * 16 + lid;
                    int cb = ks * 64 + hi;
                    bf16x8 kfr = *(const bf16x8*)(Kt[cur] + r * 128 + (cb ^ ((r & 7) << 4)));
                    a = MFMA_B16(kfr, qf[ks], a);          // swapped operands
                }
                sf[nf] = a;
            }
            __builtin_amdgcn_s_setprio(0);

            // ---- causal mask on the diagonal tile ----
            if (kt == qbMy) {
                const int qloc = wq * 16 + lid;
                #pragma unroll
                for (int nf = 0; nf < 4; ++nf) {
                    #pragma unroll
                    for (int jj = 0; jj < 4; ++jj) {
                        int keyloc = nf * 16 + h4 * 4 + jj;
                        if (keyloc > qloc) sf[nf][jj] = -1e30f;
                    }
                }
            }

            // ---- fixed-shift exp ----
            uint2 pk[4];
            #pragma unroll
            for (int nf = 0; nf < 4; ++nf) {
                float p0, p1, p2, p3;
                asm("v_exp_f32 %0, %1" : "=v"(p0) : "v"(fmaf(sf[nf][0], CLOG, NMC)));
                asm("v_exp_f32 %0, %1" : "=v"(p1) : "v"(fmaf(sf[nf][1], CLOG, NMC)));
                asm("v_exp_f32 %0, %1" : "=v"(p2) : "v"(fmaf(sf[nf][2], CLOG, NMC)));
                asm("v_exp_f32 %0, %1" : "=v"(p3) : "v"(fmaf(sf[nf][3], CLOG, NMC)));
                unsigned plo, phi;
                asm("v_cvt_pk_bf16_f32 %0, %1, %2" : "=v"(plo) : "v"(p0), "v"(p1));
                asm("v_cvt_pk_bf16_f32 %0, %1, %2" : "=v"(phi) : "v"(p2), "v"(p3));
                pk[nf].x = plo; pk[nf].y = phi;
            }

            // ---- write P row-chunk ----
            {
                const int rowq = wq * 16 + lid;
                const int swz  = (lid & 7) << 4;
                char* base = Pt[tile] + rowq * 128;
                #pragma unroll
                for (int nf = 0; nf < 4; ++nf)
                    *(uint2*)(base + ((nf * 32 + 8 * h4) ^ swz)) = pk[nf];
            }

            // ---- O += P V ; denom += P * ones ----
            #pragma unroll
            for (int ks = 0; ks < 2; ++ks) {
                int cb = ks * 64 + hi;
                int qr = wq * 16 + lid;
                bf16x8 pa = *(const bf16x8*)(Pt[tile] + qr * 128 + (cb ^ ((qr & 7) << 4)));
                __builtin_amdgcn_s_setprio(1);
                #pragma unroll
                for (int nf = 0; nf < 4; ++nf) {
                    int dr = nf * 16 + lid;
                    bf16x8 vb = *(const bf16x8*)(Vt[cur] + dr * 128 + (cb ^ ((dr & 7) << 4)));
                    o[nf] = MFMA_B16(pa, vb, o[nf]);
                }
                o5 = MFMA_B16(pa, onesv, o5);
                __builtin_amdgcn_s_setprio(0);
            }
        }
    }

    // ---- epilogue ----
    float inv[4];
    #pragma unroll
    for (int jj = 0; jj < 4; ++jj) inv[jj] = 1.0f / o5[jj];
    #pragma unroll
    for (int nf = 0; nf < 4; ++nf)
        #pragma unroll
        for (int jj = 0; jj < 4; ++jj) {
            int srow = q0My + wq * 16 + h4 * 4 + jj;
            int col  = h * 64 + nf * 16 + lid;
            AOb[((size_t)b * SEQ + srow) * DM + col] = f2bf(o[nf][jj] * inv[jj]);
        }
}

// ---------------- launch ----------------
extern "C" void kernel_launch(void* const* d_in, const int* in_sizes, int n_in,
                              void* d_out, int out_size, void* d_ws, size_t ws_size,
                              hipStream_t stream)
{
    const float* x   = (const float*)d_in[0];
    const int*   pos = (const int*)  d_in[1];
    const float* Wq  = (const float*)d_in[2];
    const float* Wk  = (const float*)d_in[3];
    const float* Wv  = (const float*)d_in[4];
    const float* Wo  = (const float*)d_in[5];
    float* out = (float*)d_out;

    const size_t M1 = 1u << 20;                 // 1M elements
    unsigned short* ws  = (unsigned short*)d_ws;
    unsigned short* Xb    = ws;                 // 4M
    unsigned short* Wqkvb = ws + 4 * M1;        // 3M (Wq|Wk|Wv rows)
    unsigned short* Wob   = ws + 7 * M1;        // 1M
    unsigned short* Qbf   = ws + 8 * M1;        // 4M  [bh][s][64]
    unsigned short* Kbf   = ws + 12 * M1;       // 4M  [bh][s][64]
    unsigned short* VTb   = ws + 16 * M1;       // 4M  [bh][64][s]
    unsigned short* AOb   = ws + 20 * M1;       // 4M  [b*s][1024]

    convert_all<<<4096, 256, 0, stream>>>(x, Wq, Wk, Wv, Wo, Xb, Wqkvb, Wob);

    // QKV projection (epilogue scatters Q,K row-major; V transposed)
    gemm_mfma<0><<<dim3(24, 32), 256, 0, stream>>>(Xb, Wqkvb, Qbf, Kbf, VTb, nullptr);

    // RoPE in place on bf16 Q/K (standalone — fusing into the GEMM epilogue
    // spilled the accumulator to scratch: R11, 270 us + 1.6 GB writes)
    rope_bf16<<<4096, 256, 0, stream>>>(Qbf, Kbf, pos);

    // flash attention (8-wave blocks, counted-vmcnt 3-deep pipeline, R18)
    flash_mfma<<<dim3(16, 32), 512, 0, stream>>>(Qbf, Kbf, VTb, AOb);

    // output projection
    gemm_mfma<1><<<dim3(8, 32), 256, 0, stream>>>(AOb, Wob, nullptr, nullptr, nullptr, out);
}

// Round 24
// 114.020 us; speedup vs baseline: 1.1355x; 1.0484x over previous
//
#include <hip/hip_runtime.h>
#include <math.h>

#define SEQ   2048
#define BATCH 2
#define NH    16
#define DKD   64
#define DM    1024
#define MTOT  (BATCH*SEQ)   // 4096

typedef short bf16x8 __attribute__((ext_vector_type(8)));      // 8 bf16 (4 VGPR)
typedef float f32x4  __attribute__((ext_vector_type(4)));      // MFMA C/D
typedef unsigned short u16x4 __attribute__((ext_vector_type(4)));
typedef unsigned short u16x8 __attribute__((ext_vector_type(8)));

#define MFMA_B16(a,b,c) __builtin_amdgcn_mfma_f32_16x16x32_bf16((a),(b),(c),0,0,0)

__device__ __forceinline__ unsigned short f2bf(float f) {
    union { float f; unsigned int u; } v; v.f = f;
    unsigned int r = v.u + 0x7FFFu + ((v.u >> 16) & 1u);   // RNE
    return (unsigned short)(r >> 16);
}
__device__ __forceinline__ float bf2f(unsigned short h) {
    union { unsigned int u; float f; } v; v.u = ((unsigned int)h) << 16;
    return v.f;
}
__device__ __forceinline__ void gload16(const void* g, void* l) {
    __builtin_amdgcn_global_load_lds(
        (const __attribute__((address_space(1))) unsigned int*)g,
        (__attribute__((address_space(3))) unsigned int*)l, 16, 0, 0);
}

// ---------------- fp32 -> bf16: x + Wq + Wk + Wv + Wo, 32 B/thread ----------------
__global__ __launch_bounds__(256)
void convert_all(const float* __restrict__ x,  const float* __restrict__ Wq,
                 const float* __restrict__ Wk, const float* __restrict__ Wv,
                 const float* __restrict__ Wo,
                 unsigned short* __restrict__ Xb, unsigned short* __restrict__ Wqkvb,
                 unsigned short* __restrict__ Wob)
{
    int i = blockIdx.x * 256 + threadIdx.x;          // 0 .. 1M-1, each 8 floats
    const float* src;
    unsigned short* dst;
    size_t off;
    if (i < (1 << 19)) {                             // x: 4M floats = 512K groups
        src = x; dst = Xb; off = (size_t)i;
    } else {
        int j = i - (1 << 19);
        int wsel = j >> 17;                          // 0..3
        off = (size_t)(j & ((1 << 17) - 1));
        src = (wsel == 0) ? Wq : (wsel == 1) ? Wk : (wsel == 2) ? Wv : Wo;
        dst = (wsel < 3) ? Wqkvb + (size_t)wsel * (1u << 20) : Wob;
    }
    float4 v0 = ((const float4*)src)[off * 2];
    float4 v1 = ((const float4*)src)[off * 2 + 1];
    u16x8 o = { f2bf(v0.x), f2bf(v0.y), f2bf(v0.z), f2bf(v0.w),
                f2bf(v1.x), f2bf(v1.y), f2bf(v1.z), f2bf(v1.w) };
    *(u16x8*)&dst[off * 8] = o;
}

// ---------------- RoPE in place on bf16 Q/K  [bh][s][64], 16 B/thread ----------------
__global__ __launch_bounds__(256)
void rope_bf16(unsigned short* __restrict__ Qb, unsigned short* __restrict__ Kb,
               const int* __restrict__ pos)
{
    int idx = blockIdx.x * 256 + threadIdx.x;    // 0..1M-1 (Q then K), each 8 bf16
    int tsel = idx >> 19;
    int i = idx & ((1 << 19) - 1);
    unsigned short* base = tsel ? Kb : Qb;
    int d8 = i & 7;
    int s  = (i >> 3) & (SEQ - 1);
    float P = (float)pos[s];
    const float NEG_L2 = -0.41524101186092103f;  // -log2(10000)/32

    u16x8 v = *(u16x8*)&base[(size_t)i * 8];
    u16x8 o;
    #pragma unroll
    for (int k = 0; k < 4; ++k) {
        int pi = d8 * 4 + k;
        float ang = P * exp2f((float)pi * NEG_L2);
        float sn, cs;
        sincosf(ang, &sn, &cs);
        float e0 = bf2f(v[2*k]), e1 = bf2f(v[2*k + 1]);
        o[2*k]     = f2bf(e0 * cs - e1 * sn);
        o[2*k + 1] = f2bf(e0 * sn + e1 * cs);
    }
    *(u16x8*)&base[(size_t)i * 8] = o;
}

// ---------------- MFMA GEMM: 3-deep counted-vmcnt pipeline + T2 read-swizzle -------
// (exact R19 kernel — measured 42.3 us, 0 bank conflicts.)
template<int MODE>
__global__ __launch_bounds__(256)
void gemm_mfma(const unsigned short* __restrict__ A, const unsigned short* __restrict__ B,
               unsigned short* __restrict__ Qb, unsigned short* __restrict__ Kb,
               unsigned short* __restrict__ VTb, float* __restrict__ Cf)
{
    const int t = threadIdx.x;
    const int w = t >> 6, l = t & 63, lid = l & 15, hi = (l >> 4) * 16;
    const int wm = w >> 1, wn = w & 1;
    const int m0 = blockIdx.y * 128, n0 = blockIdx.x * 128;

    __shared__ __align__(16) char At[3][8192];
    __shared__ __align__(16) char Bt[3][8192];

    f32x4 acc[4][4];
    const f32x4 z4 = {0.f, 0.f, 0.f, 0.f};
    #pragma unroll
    for (int i = 0; i < 4; ++i)
        #pragma unroll
        for (int j = 0; j < 4; ++j) acc[i][j] = z4;

    const char* Ab = (const char*)A;
    const char* Bb = (const char*)B;

    auto stage = [&](int buf, int kt) {
        const int kbyte = kt * 64;
        #pragma unroll
        for (int i = 0; i < 2; ++i) {
            int o   = i * 4096 + t * 16;
            int row = o >> 6, cb = o & 63;
            int sw  = ((row >> 1) & 3) << 4;
            char* lbase_a = At[buf] + i * 4096 + (t >> 6) * 1024;
            char* lbase_b = Bt[buf] + i * 4096 + (t >> 6) * 1024;
            gload16(Ab + (size_t)(m0 + row) * 2048 + kbyte + (cb ^ sw), lbase_a);
            gload16(Bb + (size_t)(n0 + row) * 2048 + kbyte + (cb ^ sw), lbase_b);
        }
    };

    const int NKT = DM / 32;
    stage(0, 0);
    stage(1, 1);

    for (int kt = 0; kt < NKT; ++kt) {
        const int cur = kt % 3;
        if (kt == NKT - 1) asm volatile("s_waitcnt vmcnt(0)" ::: "memory");
        else               asm volatile("s_waitcnt vmcnt(4)" ::: "memory");
        __builtin_amdgcn_s_barrier();
        if (kt + 2 < NKT) stage((kt + 2) % 3, kt + 2);

        bf16x8 af[4], bfr[4];
        #pragma unroll
        for (int mf = 0; mf < 4; ++mf) {
            int ar = wm * 64 + mf * 16 + lid;
            af[mf] = *(const bf16x8*)(At[cur] + ar * 64 + (hi ^ (((ar >> 1) & 3) << 4)));
        }
        #pragma unroll
        for (int nf = 0; nf < 4; ++nf) {
            int br = wn * 64 + nf * 16 + lid;
            bfr[nf] = *(const bf16x8*)(Bt[cur] + br * 64 + (hi ^ (((br >> 1) & 3) << 4)));
        }
        __builtin_amdgcn_s_setprio(1);
        #pragma unroll
        for (int mf = 0; mf < 4; ++mf)
            #pragma unroll
            for (int nf = 0; nf < 4; ++nf)
                acc[mf][nf] = MFMA_B16(af[mf], bfr[nf], acc[mf][nf]);
        __builtin_amdgcn_s_setprio(0);
    }

    if (MODE == 1) {
        #pragma unroll
        for (int mf = 0; mf < 4; ++mf)
            #pragma unroll
            for (int nf = 0; nf < 4; ++nf) {
                int ncol = n0 + wn * 64 + nf * 16 + lid;
                #pragma unroll
                for (int jj = 0; jj < 4; ++jj) {
                    int mrow = m0 + wm * 64 + mf * 16 + (l >> 4) * 4 + jj;
                    Cf[(size_t)mrow * DM + ncol] = acc[mf][nf][jj];
                }
            }
    } else {
        const int z = n0 >> 10;                  // 0:Q 1:K 2:V
        const int nbase = n0 & 1023;
        #pragma unroll
        for (int mf = 0; mf < 4; ++mf)
            #pragma unroll
            for (int nf = 0; nf < 4; ++nf) {
                int ncol = nbase + wn * 64 + nf * 16 + lid;
                int h = ncol >> 6, d = ncol & 63;
                int mbase = m0 + wm * 64 + mf * 16 + (l >> 4) * 4;
                int b = mbase >> 11, s0v = mbase & 2047;
                if (z == 2) {
                    u16x4 pk = { f2bf(acc[mf][nf][0]), f2bf(acc[mf][nf][1]),
                                 f2bf(acc[mf][nf][2]), f2bf(acc[mf][nf][3]) };
                    *(u16x4*)&VTb[((size_t)(b * NH + h) * DKD + d) * SEQ + s0v] = pk;
                } else {
                    unsigned short* dst = (z == 0) ? Qb : Kb;
                    #pragma unroll
                    for (int jj = 0; jj < 4; ++jj)
                        dst[((size_t)(b * NH + h) * SEQ + (s0v + jj)) * DKD + d] =
                            f2bf(acc[mf][nf][jj]);
                }
            }
    }
}

// ---------------- MFMA flash attention: key-split 16-wave blocks ----------------
// 1024 thr = 16 waves; wave (tile = w8>>3, wq = (w8>>1)&3, kh = w8&1):
//   q-rows wq*16..+16 of q-tile {A,B}, keys kh*32..+32 of each K/V tile.
// Per-wave round work HALVED vs R18 (QK 4 MFMA, exp 8, PV 5 MFMA, 2 P-stores) --
// the serial chain that sets round latency. Each (q,d) accumulated by wave pair
// (kh=0,1) over disjoint key halves; merged ONCE at epilogue via dead K/V LDS.
// Staging: 1 gload16/thread (waves 0-7 K, 8-15 V -> wave-uniform vmcnt); 3-deep,
// counted vmcnt(1). Same grid decode as R18. LDS 64 KB; launch_bounds(1024,8)
// targets <=64 VGPR -> 2 blocks = 32 waves/CU.
__global__ __launch_bounds__(1024, 8)
void flash_mfma(const unsigned short* __restrict__ Qb, const unsigned short* __restrict__ Kb,
                const unsigned short* __restrict__ VTb, unsigned short* __restrict__ AOb)
{
    const int L  = blockIdx.y * 16 + blockIdx.x;     // 0..511
    const int g  = L >> 8, c = L & 255;
    const int j  = c & 15;
    const int bh = (g << 4) | (c >> 4);
    const int b = bh >> 4, h = bh & 15;
    const int qbA = g ? (30 - 2 * j) : (2 * j);
    const int qbB = qbA + 1;

    const int t = threadIdx.x;
    const int w8 = t >> 6, l = t & 63, lid = l & 15, hi = (l >> 4) * 16;
    const int h4 = l >> 4;
    const int tile = w8 >> 3, wq = (w8 >> 1) & 3, kh = w8 & 1;
    const int qbMy = tile ? qbB : qbA;
    const int ntMy = qbMy + 1;
    const int q0My = qbMy * 64;
    const int ntB  = qbB + 1;                        // loop bound (B = A+1), >= 2

    __shared__ __align__(16) char Kt[3][8192];
    __shared__ __align__(16) char Vt[3][8192];
    __shared__ __align__(16) char Pt[2][8192];       // per-tile P

    const char* Kbh = (const char*)(Kb  + (size_t)bh * SEQ * DKD);
    const char* Vbh = (const char*)(VTb + (size_t)bh * SEQ * DKD);
    const char* Qbh = (const char*)(Qb  + (size_t)bh * SEQ * DKD);

    const f32x4 z4 = {0.f, 0.f, 0.f, 0.f};
    const int qrow = wq * 16 + lid;
    const float CLOG = 0.18033688011112042f;     // log2(e)/8
    const float NMC  = -17.312340490667560f;     // -12*log2(e)

    bf16x8 onesv;
    #pragma unroll
    for (int i = 0; i < 8; ++i) onesv[i] = (short)0x3F80;   // bf16 1.0

    bf16x8 qf[2];
    qf[0] = *(const bf16x8*)(Qbh + (size_t)(q0My + qrow) * 128 + 0  + hi);
    qf[1] = *(const bf16x8*)(Qbh + (size_t)(q0My + qrow) * 128 + 64 + hi);

    f32x4 o[4], o5;
    #pragma unroll
    for (int nf = 0; nf < 4; ++nf) o[nf] = z4;
    o5 = z4;

    // 1024 threads: t<512 stage K (8 KB), t>=512 stage V (8 KB); 1 gload16/thread
    auto stage = [&](int buf, int kt) {
        if (t < 512) {
            int o_ = t * 16, row = o_ >> 7, cl = o_ & 127, sw = (row & 7) << 4;
            gload16(Kbh + (size_t)(kt * 64 + row) * 128 + (cl ^ sw),
                    Kt[buf] + w8 * 1024);
        } else {
            int o_ = (t - 512) * 16, row = o_ >> 7, cl = o_ & 127, sw = (row & 7) << 4;
            gload16(Vbh + (size_t)row * (SEQ * 2) + kt * 128 + (cl ^ sw),
                    Vt[buf] + (w8 - 8) * 1024);
        }
    };

    stage(0, 0);
    stage(1, 1);

    for (int kt = 0; kt < ntB; ++kt) {
        const int cur = kt % 3;

        if (kt == ntB - 1) asm volatile("s_waitcnt vmcnt(0)" ::: "memory");
        else               asm volatile("s_waitcnt vmcnt(1)" ::: "memory");
        __builtin_amdgcn_s_barrier();
        if (kt + 2 < ntB) stage((kt + 2) % 3, kt + 2);

        if (kt < ntMy) {
            // ---- S^T = K Q^T, my 32 keys: lane holds S[key=kh*32+nf*16+4*h4+jj][q] ----
            f32x4 sf[2];
            __builtin_amdgcn_s_setprio(1);
            #pragma unroll
            for (int nf = 0; nf < 2; ++nf) {
                f32x4 a = z4;
                #pragma unroll
                for (int ks = 0; ks < 2; ++ks) {
                    int r  = kh * 32 + nf * 16 + lid;
                    int cb = ks * 64 + hi;
                    bf16x8 kfr = *(const bf16x8*)(Kt[cur] + r * 128 + (cb ^ ((r & 7) << 4)));
                    a = MFMA_B16(kfr, qf[ks], a);          // swapped operands
                }
                sf[nf] = a;
            }
            __builtin_amdgcn_s_setprio(0);

            // ---- causal mask on the diagonal tile ----
            if (kt == qbMy) {
                const int qloc = wq * 16 + lid;
                #pragma unroll
                for (int nf = 0; nf < 2; ++nf) {
                    #pragma unroll
                    for (int jj = 0; jj < 4; ++jj) {
                        int keyloc = kh * 32 + nf * 16 + h4 * 4 + jj;
                        if (keyloc > qloc) sf[nf][jj] = -1e30f;
                    }
                }
            }

            // ---- fixed-shift exp ----
            uint2 pk[2];
            #pragma unroll
            for (int nf = 0; nf < 2; ++nf) {
                float p0, p1, p2, p3;
                asm("v_exp_f32 %0, %1" : "=v"(p0) : "v"(fmaf(sf[nf][0], CLOG, NMC)));
                asm("v_exp_f32 %0, %1" : "=v"(p1) : "v"(fmaf(sf[nf][1], CLOG, NMC)));
                asm("v_exp_f32 %0, %1" : "=v"(p2) : "v"(fmaf(sf[nf][2], CLOG, NMC)));
                asm("v_exp_f32 %0, %1" : "=v"(p3) : "v"(fmaf(sf[nf][3], CLOG, NMC)));
                unsigned plo, phi;
                asm("v_cvt_pk_bf16_f32 %0, %1, %2" : "=v"(plo) : "v"(p0), "v"(p1));
                asm("v_cvt_pk_bf16_f32 %0, %1, %2" : "=v"(phi) : "v"(p2), "v"(p3));
                pk[nf].x = plo; pk[nf].y = phi;
            }

            // ---- write my P key-half (rows & columns wave-private) ----
            {
                const int swz  = (lid & 7) << 4;
                char* base = Pt[tile] + qrow * 128;
                #pragma unroll
                for (int nf = 0; nf < 2; ++nf)
                    *(uint2*)(base + ((kh * 64 + nf * 32 + 8 * h4) ^ swz)) = pk[nf];
            }

            // ---- O += P V over my 32 keys ; denom += P * ones ----
            {
                int cb = kh * 64 + hi;
                bf16x8 pa = *(const bf16x8*)(Pt[tile] + qrow * 128 + (cb ^ ((qrow & 7) << 4)));
                __builtin_amdgcn_s_setprio(1);
                #pragma unroll
                for (int nf = 0; nf < 4; ++nf) {
                    int dr = nf * 16 + lid;
                    bf16x8 vb = *(const bf16x8*)(Vt[cur] + dr * 128 + (cb ^ ((dr & 7) << 4)));
                    o[nf] = MFMA_B16(pa, vb, o[nf]);
                }
                o5 = MFMA_B16(pa, onesv, o5);
                __builtin_amdgcn_s_setprio(0);
            }
        }
    }

    // ---- epilogue: merge key-half partials (waves w8, w8^1), normalize, store ----
    __syncthreads();                                 // K/V LDS now dead -> scratch
    const int ww = w8 >> 1;                          // pair index 0..7
    char* scr = (ww < 4) ? ((char*)Kt + ww * 5120)
                         : ((char*)Vt + (ww - 4) * 5120);
    if (kh == 1) {                                   // writer: 5 x float4 per lane
        #pragma unroll
        for (int nf = 0; nf < 4; ++nf)
            *(f32x4*)(scr + l * 80 + nf * 16) = o[nf];
        *(f32x4*)(scr + l * 80 + 64) = o5;
    }
    __syncthreads();
    if (kh == 0) {
        #pragma unroll
        for (int nf = 0; nf < 4; ++nf) {
            f32x4 po = *(const f32x4*)(scr + l * 80 + nf * 16);
            o[nf] += po;
        }
        f32x4 po5 = *(const f32x4*)(scr + l * 80 + 64);
        o5 += po5;

        float inv[4];
        #pragma unroll
        for (int jj = 0; jj < 4; ++jj) inv[jj] = 1.0f / o5[jj];
        #pragma unroll
        for (int nf = 0; nf < 4; ++nf)
            #pragma unroll
            for (int jj = 0; jj < 4; ++jj) {
                int srow = q0My + wq * 16 + h4 * 4 + jj;
                int col  = h * 64 + nf * 16 + lid;
                AOb[((size_t)b * SEQ + srow) * DM + col] = f2bf(o[nf][jj] * inv[jj]);
            }
    }
}

// ---------------- launch ----------------
extern "C" void kernel_launch(void* const* d_in, const int* in_sizes, int n_in,
                              void* d_out, int out_size, void* d_ws, size_t ws_size,
                              hipStream_t stream)
{
    const float* x   = (const float*)d_in[0];
    const int*   pos = (const int*)  d_in[1];
    const float* Wq  = (const float*)d_in[2];
    const float* Wk  = (const float*)d_in[3];
    const float* Wv  = (const float*)d_in[4];
    const float* Wo  = (const float*)d_in[5];
    float* out = (float*)d_out;

    const size_t M1 = 1u << 20;                 // 1M elements
    unsigned short* ws  = (unsigned short*)d_ws;
    unsigned short* Xb    = ws;                 // 4M
    unsigned short* Wqkvb = ws + 4 * M1;        // 3M (Wq|Wk|Wv rows)
    unsigned short* Wob   = ws + 7 * M1;        // 1M
    unsigned short* Qbf   = ws + 8 * M1;        // 4M  [bh][s][64]
    unsigned short* Kbf   = ws + 12 * M1;       // 4M  [bh][s][64]
    unsigned short* VTb   = ws + 16 * M1;       // 4M  [bh][64][s]
    unsigned short* AOb   = ws + 20 * M1;       // 4M  [b*s][1024]

    convert_all<<<4096, 256, 0, stream>>>(x, Wq, Wk, Wv, Wo, Xb, Wqkvb, Wob);

    // QKV projection (epilogue scatters Q,K row-major; V transposed)
    gemm_mfma<0><<<dim3(24, 32), 256, 0, stream>>>(Xb, Wqkvb, Qbf, Kbf, VTb, nullptr);

    // RoPE in place on bf16 Q/K
    rope_bf16<<<4096, 256, 0, stream>>>(Qbf, Kbf, pos);

    // flash attention (16-wave key-split blocks, counted-vmcnt 3-deep pipeline)
    flash_mfma<<<dim3(16, 32), 1024, 0, stream>>>(Qbf, Kbf, VTb, AOb);

    // output projection
    gemm_mfma<1><<<dim3(8, 32), 256, 0, stream>>>(AOb, Wob, nullptr, nullptr, nullptr, out);
}

// Round 25
// 107.167 us; speedup vs baseline: 1.2081x; 1.0639x over previous
//
#include <hip/hip_runtime.h>
#include <math.h>

#define SEQ   2048
#define BATCH 2
#define NH    16
#define DKD   64
#define DM    1024
#define MTOT  (BATCH*SEQ)   // 4096

typedef short bf16x8 __attribute__((ext_vector_type(8)));      // 8 bf16 (4 VGPR)
typedef float f32x4  __attribute__((ext_vector_type(4)));      // MFMA C/D
typedef unsigned short u16x4 __attribute__((ext_vector_type(4)));
typedef unsigned short u16x8 __attribute__((ext_vector_type(8)));

#define MFMA_B16(a,b,c) __builtin_amdgcn_mfma_f32_16x16x32_bf16((a),(b),(c),0,0,0)

__device__ __forceinline__ unsigned short f2bf(float f) {
    union { float f; unsigned int u; } v; v.f = f;
    unsigned int r = v.u + 0x7FFFu + ((v.u >> 16) & 1u);   // RNE
    return (unsigned short)(r >> 16);
}
__device__ __forceinline__ float bf2f(unsigned short h) {
    union { unsigned int u; float f; } v; v.u = ((unsigned int)h) << 16;
    return v.f;
}
__device__ __forceinline__ void gload16(const void* g, void* l) {
    __builtin_amdgcn_global_load_lds(
        (const __attribute__((address_space(1))) unsigned int*)g,
        (__attribute__((address_space(3))) unsigned int*)l, 16, 0, 0);
}

// ---------------- fp32 -> bf16: x + Wq + Wk + Wv + Wo, 32 B/thread ----------------
__global__ __launch_bounds__(256)
void convert_all(const float* __restrict__ x,  const float* __restrict__ Wq,
                 const float* __restrict__ Wk, const float* __restrict__ Wv,
                 const float* __restrict__ Wo,
                 unsigned short* __restrict__ Xb, unsigned short* __restrict__ Wqkvb,
                 unsigned short* __restrict__ Wob)
{
    int i = blockIdx.x * 256 + threadIdx.x;          // 0 .. 1M-1, each 8 floats
    const float* src;
    unsigned short* dst;
    size_t off;
    if (i < (1 << 19)) {                             // x: 4M floats = 512K groups
        src = x; dst = Xb; off = (size_t)i;
    } else {
        int j = i - (1 << 19);
        int wsel = j >> 17;                          // 0..3
        off = (size_t)(j & ((1 << 17) - 1));
        src = (wsel == 0) ? Wq : (wsel == 1) ? Wk : (wsel == 2) ? Wv : Wo;
        dst = (wsel < 3) ? Wqkvb + (size_t)wsel * (1u << 20) : Wob;
    }
    float4 v0 = ((const float4*)src)[off * 2];
    float4 v1 = ((const float4*)src)[off * 2 + 1];
    u16x8 o = { f2bf(v0.x), f2bf(v0.y), f2bf(v0.z), f2bf(v0.w),
                f2bf(v1.x), f2bf(v1.y), f2bf(v1.z), f2bf(v1.w) };
    *(u16x8*)&dst[off * 8] = o;
}

// ---------------- RoPE in place on bf16 Q/K  [bh][s][64], 16 B/thread ----------------
__global__ __launch_bounds__(256)
void rope_bf16(unsigned short* __restrict__ Qb, unsigned short* __restrict__ Kb,
               const int* __restrict__ pos)
{
    int idx = blockIdx.x * 256 + threadIdx.x;    // 0..1M-1 (Q then K), each 8 bf16
    int tsel = idx >> 19;
    int i = idx & ((1 << 19) - 1);
    unsigned short* base = tsel ? Kb : Qb;
    int d8 = i & 7;
    int s  = (i >> 3) & (SEQ - 1);
    float P = (float)pos[s];
    const float NEG_L2 = -0.41524101186092103f;  // -log2(10000)/32

    u16x8 v = *(u16x8*)&base[(size_t)i * 8];
    u16x8 o;
    #pragma unroll
    for (int k = 0; k < 4; ++k) {
        int pi = d8 * 4 + k;
        float ang = P * exp2f((float)pi * NEG_L2);
        float sn, cs;
        sincosf(ang, &sn, &cs);
        float e0 = bf2f(v[2*k]), e1 = bf2f(v[2*k + 1]);
        o[2*k]     = f2bf(e0 * cs - e1 * sn);
        o[2*k + 1] = f2bf(e0 * sn + e1 * cs);
    }
    *(u16x8*)&base[(size_t)i * 8] = o;
}

// ---------------- MFMA GEMM: 8-wave 64x32 sub-tiles (R24-flash mechanism) ----------
// C[M][N] = A[M][K] x B[N][K]^T, bf16 in / f32 acc; 128x128 tile, BK=32, 512 thr.
// Wave (wm = w>>2, wn = w&3) owns a 64x32 output: 6 ds_read + 8 MFMA per round --
// HALF the per-wave serial chain of the 4-wave version -- at 3 blocks/CU the CU now
// carries 24 waves (was 12). Staging: 1 A + 1 B gload16 per thread (512 x 16 B =
// full tile); 3-deep counted vmcnt(2). T2 read-swizzle unchanged (0 conflicts, R19).
// MODE 0: N=3072, epilogue scatters Q,K ([bh][s][d]) and V transposed ([bh][d][s])
// MODE 1: N=1024, epilogue writes fp32 row-major C
template<int MODE>
__global__ __launch_bounds__(512)
void gemm_mfma(const unsigned short* __restrict__ A, const unsigned short* __restrict__ B,
               unsigned short* __restrict__ Qb, unsigned short* __restrict__ Kb,
               unsigned short* __restrict__ VTb, float* __restrict__ Cf)
{
    const int t = threadIdx.x;
    const int w = t >> 6, l = t & 63, lid = l & 15, hi = (l >> 4) * 16;
    const int wm = w >> 2, wn = w & 3;               // 2 x 4 wave grid
    const int m0 = blockIdx.y * 128, n0 = blockIdx.x * 128;

    __shared__ __align__(16) char At[3][8192];       // [128 rows][32 k] bf16, 64 B rows
    __shared__ __align__(16) char Bt[3][8192];

    f32x4 acc[4][2];
    const f32x4 z4 = {0.f, 0.f, 0.f, 0.f};
    #pragma unroll
    for (int i = 0; i < 4; ++i)
        #pragma unroll
        for (int j2 = 0; j2 < 2; ++j2) acc[i][j2] = z4;

    const char* Ab = (const char*)A;
    const char* Bb = (const char*)B;

    auto stage = [&](int buf, int kt) {              // 2 gload16 per thread
        const int kbyte = kt * 64;
        int o   = t * 16;                            // 0..8191
        int row = o >> 6, cb = o & 63;
        int sw  = ((row >> 1) & 3) << 4;             // T2: pre-swizzle global source
        gload16(Ab + (size_t)(m0 + row) * 2048 + kbyte + (cb ^ sw), At[buf] + w * 1024);
        gload16(Bb + (size_t)(n0 + row) * 2048 + kbyte + (cb ^ sw), Bt[buf] + w * 1024);
    };

    const int NKT = DM / 32;                         // 32
    stage(0, 0);
    stage(1, 1);

    for (int kt = 0; kt < NKT; ++kt) {
        const int cur = kt % 3;
        if (kt == NKT - 1) asm volatile("s_waitcnt vmcnt(0)" ::: "memory");
        else               asm volatile("s_waitcnt vmcnt(2)" ::: "memory");
        __builtin_amdgcn_s_barrier();                // tile kt resident block-wide;
                                                     // buf[(kt+2)%3] free of readers
        if (kt + 2 < NKT) stage((kt + 2) % 3, kt + 2);

        bf16x8 af[4], bfr[2];
        #pragma unroll
        for (int mf = 0; mf < 4; ++mf) {
            int ar = wm * 64 + mf * 16 + lid;
            af[mf] = *(const bf16x8*)(At[cur] + ar * 64 + (hi ^ (((ar >> 1) & 3) << 4)));
        }
        #pragma unroll
        for (int nf = 0; nf < 2; ++nf) {
            int br = wn * 32 + nf * 16 + lid;
            bfr[nf] = *(const bf16x8*)(Bt[cur] + br * 64 + (hi ^ (((br >> 1) & 3) << 4)));
        }
        __builtin_amdgcn_s_setprio(1);
        #pragma unroll
        for (int mf = 0; mf < 4; ++mf)
            #pragma unroll
            for (int nf = 0; nf < 2; ++nf)
                acc[mf][nf] = MFMA_B16(af[mf], bfr[nf], acc[mf][nf]);
        __builtin_amdgcn_s_setprio(0);
    }

    if (MODE == 1) {
        #pragma unroll
        for (int mf = 0; mf < 4; ++mf)
            #pragma unroll
            for (int nf = 0; nf < 2; ++nf) {
                int ncol = n0 + wn * 32 + nf * 16 + lid;
                #pragma unroll
                for (int jj = 0; jj < 4; ++jj) {
                    int mrow = m0 + wm * 64 + mf * 16 + (l >> 4) * 4 + jj;
                    Cf[(size_t)mrow * DM + ncol] = acc[mf][nf][jj];
                }
            }
    } else {
        const int z = n0 >> 10;                      // 0:Q 1:K 2:V
        const int nbase = n0 & 1023;
        #pragma unroll
        for (int mf = 0; mf < 4; ++mf)
            #pragma unroll
            for (int nf = 0; nf < 2; ++nf) {
                int ncol = nbase + wn * 32 + nf * 16 + lid;
                int h = ncol >> 6, d = ncol & 63;
                int mbase = m0 + wm * 64 + mf * 16 + (l >> 4) * 4;
                int b = mbase >> 11, s0v = mbase & 2047;
                if (z == 2) {
                    u16x4 pk = { f2bf(acc[mf][nf][0]), f2bf(acc[mf][nf][1]),
                                 f2bf(acc[mf][nf][2]), f2bf(acc[mf][nf][3]) };
                    *(u16x4*)&VTb[((size_t)(b * NH + h) * DKD + d) * SEQ + s0v] = pk;
                } else {
                    unsigned short* dst = (z == 0) ? Qb : Kb;
                    #pragma unroll
                    for (int jj = 0; jj < 4; ++jj)
                        dst[((size_t)(b * NH + h) * SEQ + (s0v + jj)) * DKD + d] =
                            f2bf(acc[mf][nf][jj]);
                }
            }
    }
}

// ---------------- MFMA flash attention: key-split 16-wave blocks (exact R24) -------
__global__ __launch_bounds__(1024, 8)
void flash_mfma(const unsigned short* __restrict__ Qb, const unsigned short* __restrict__ Kb,
                const unsigned short* __restrict__ VTb, unsigned short* __restrict__ AOb)
{
    const int L  = blockIdx.y * 16 + blockIdx.x;     // 0..511
    const int g  = L >> 8, c = L & 255;
    const int j  = c & 15;
    const int bh = (g << 4) | (c >> 4);
    const int b = bh >> 4, h = bh & 15;
    const int qbA = g ? (30 - 2 * j) : (2 * j);
    const int qbB = qbA + 1;

    const int t = threadIdx.x;
    const int w8 = t >> 6, l = t & 63, lid = l & 15, hi = (l >> 4) * 16;
    const int h4 = l >> 4;
    const int tile = w8 >> 3, wq = (w8 >> 1) & 3, kh = w8 & 1;
    const int qbMy = tile ? qbB : qbA;
    const int ntMy = qbMy + 1;
    const int q0My = qbMy * 64;
    const int ntB  = qbB + 1;                        // loop bound (B = A+1), >= 2

    __shared__ __align__(16) char Kt[3][8192];
    __shared__ __align__(16) char Vt[3][8192];
    __shared__ __align__(16) char Pt[2][8192];       // per-tile P

    const char* Kbh = (const char*)(Kb  + (size_t)bh * SEQ * DKD);
    const char* Vbh = (const char*)(VTb + (size_t)bh * SEQ * DKD);
    const char* Qbh = (const char*)(Qb  + (size_t)bh * SEQ * DKD);

    const f32x4 z4 = {0.f, 0.f, 0.f, 0.f};
    const int qrow = wq * 16 + lid;
    const float CLOG = 0.18033688011112042f;     // log2(e)/8
    const float NMC  = -17.312340490667560f;     // -12*log2(e)

    bf16x8 onesv;
    #pragma unroll
    for (int i = 0; i < 8; ++i) onesv[i] = (short)0x3F80;   // bf16 1.0

    bf16x8 qf[2];
    qf[0] = *(const bf16x8*)(Qbh + (size_t)(q0My + qrow) * 128 + 0  + hi);
    qf[1] = *(const bf16x8*)(Qbh + (size_t)(q0My + qrow) * 128 + 64 + hi);

    f32x4 o[4], o5;
    #pragma unroll
    for (int nf = 0; nf < 4; ++nf) o[nf] = z4;
    o5 = z4;

    auto stage = [&](int buf, int kt) {
        if (t < 512) {
            int o_ = t * 16, row = o_ >> 7, cl = o_ & 127, sw = (row & 7) << 4;
            gload16(Kbh + (size_t)(kt * 64 + row) * 128 + (cl ^ sw),
                    Kt[buf] + w8 * 1024);
        } else {
            int o_ = (t - 512) * 16, row = o_ >> 7, cl = o_ & 127, sw = (row & 7) << 4;
            gload16(Vbh + (size_t)row * (SEQ * 2) + kt * 128 + (cl ^ sw),
                    Vt[buf] + (w8 - 8) * 1024);
        }
    };

    stage(0, 0);
    stage(1, 1);

    for (int kt = 0; kt < ntB; ++kt) {
        const int cur = kt % 3;

        if (kt == ntB - 1) asm volatile("s_waitcnt vmcnt(0)" ::: "memory");
        else               asm volatile("s_waitcnt vmcnt(1)" ::: "memory");
        __builtin_amdgcn_s_barrier();
        if (kt + 2 < ntB) stage((kt + 2) % 3, kt + 2);

        if (kt < ntMy) {
            f32x4 sf[2];
            __builtin_amdgcn_s_setprio(1);
            #pragma unroll
            for (int nf = 0; nf < 2; ++nf) {
                f32x4 a = z4;
                #pragma unroll
                for (int ks = 0; ks < 2; ++ks) {
                    int r  = kh * 32 + nf * 16 + lid;
                    int cb = ks * 64 + hi;
                    bf16x8 kfr = *(const bf16x8*)(Kt[cur] + r * 128 + (cb ^ ((r & 7) << 4)));
                    a = MFMA_B16(kfr, qf[ks], a);          // swapped operands
                }
                sf[nf] = a;
            }
            __builtin_amdgcn_s_setprio(0);

            if (kt == qbMy) {
                const int qloc = wq * 16 + lid;
                #pragma unroll
                for (int nf = 0; nf < 2; ++nf) {
                    #pragma unroll
                    for (int jj = 0; jj < 4; ++jj) {
                        int keyloc = kh * 32 + nf * 16 + h4 * 4 + jj;
                        if (keyloc > qloc) sf[nf][jj] = -1e30f;
                    }
                }
            }

            uint2 pk[2];
            #pragma unroll
            for (int nf = 0; nf < 2; ++nf) {
                float p0, p1, p2, p3;
                asm("v_exp_f32 %0, %1" : "=v"(p0) : "v"(fmaf(sf[nf][0], CLOG, NMC)));
                asm("v_exp_f32 %0, %1" : "=v"(p1) : "v"(fmaf(sf[nf][1], CLOG, NMC)));
                asm("v_exp_f32 %0, %1" : "=v"(p2) : "v"(fmaf(sf[nf][2], CLOG, NMC)));
                asm("v_exp_f32 %0, %1" : "=v"(p3) : "v"(fmaf(sf[nf][3], CLOG, NMC)));
                unsigned plo, phi;
                asm("v_cvt_pk_bf16_f32 %0, %1, %2" : "=v"(plo) : "v"(p0), "v"(p1));
                asm("v_cvt_pk_bf16_f32 %0, %1, %2" : "=v"(phi) : "v"(p2), "v"(p3));
                pk[nf].x = plo; pk[nf].y = phi;
            }

            {
                const int swz  = (lid & 7) << 4;
                char* base = Pt[tile] + qrow * 128;
                #pragma unroll
                for (int nf = 0; nf < 2; ++nf)
                    *(uint2*)(base + ((kh * 64 + nf * 32 + 8 * h4) ^ swz)) = pk[nf];
            }

            {
                int cb = kh * 64 + hi;
                bf16x8 pa = *(const bf16x8*)(Pt[tile] + qrow * 128 + (cb ^ ((qrow & 7) << 4)));
                __builtin_amdgcn_s_setprio(1);
                #pragma unroll
                for (int nf = 0; nf < 4; ++nf) {
                    int dr = nf * 16 + lid;
                    bf16x8 vb = *(const bf16x8*)(Vt[cur] + dr * 128 + (cb ^ ((dr & 7) << 4)));
                    o[nf] = MFMA_B16(pa, vb, o[nf]);
                }
                o5 = MFMA_B16(pa, onesv, o5);
                __builtin_amdgcn_s_setprio(0);
            }
        }
    }

    // ---- epilogue: merge key-half partials (waves w8, w8^1), normalize, store ----
    __syncthreads();                                 // K/V LDS now dead -> scratch
    const int ww = w8 >> 1;                          // pair index 0..7
    char* scr = (ww < 4) ? ((char*)Kt + ww * 5120)
                         : ((char*)Vt + (ww - 4) * 5120);
    if (kh == 1) {                                   // writer: 5 x float4 per lane
        #pragma unroll
        for (int nf = 0; nf < 4; ++nf)
            *(f32x4*)(scr + l * 80 + nf * 16) = o[nf];
        *(f32x4*)(scr + l * 80 + 64) = o5;
    }
    __syncthreads();
    if (kh == 0) {
        #pragma unroll
        for (int nf = 0; nf < 4; ++nf) {
            f32x4 po = *(const f32x4*)(scr + l * 80 + nf * 16);
            o[nf] += po;
        }
        f32x4 po5 = *(const f32x4*)(scr + l * 80 + 64);
        o5 += po5;

        float inv[4];
        #pragma unroll
        for (int jj = 0; jj < 4; ++jj) inv[jj] = 1.0f / o5[jj];
        #pragma unroll
        for (int nf = 0; nf < 4; ++nf)
            #pragma unroll
            for (int jj = 0; jj < 4; ++jj) {
                int srow = q0My + wq * 16 + h4 * 4 + jj;
                int col  = h * 64 + nf * 16 + lid;
                AOb[((size_t)b * SEQ + srow) * DM + col] = f2bf(o[nf][jj] * inv[jj]);
            }
    }
}

// ---------------- launch ----------------
extern "C" void kernel_launch(void* const* d_in, const int* in_sizes, int n_in,
                              void* d_out, int out_size, void* d_ws, size_t ws_size,
                              hipStream_t stream)
{
    const float* x   = (const float*)d_in[0];
    const int*   pos = (const int*)  d_in[1];
    const float* Wq  = (const float*)d_in[2];
    const float* Wk  = (const float*)d_in[3];
    const float* Wv  = (const float*)d_in[4];
    const float* Wo  = (const float*)d_in[5];
    float* out = (float*)d_out;

    const size_t M1 = 1u << 20;                 // 1M elements
    unsigned short* ws  = (unsigned short*)d_ws;
    unsigned short* Xb    = ws;                 // 4M
    unsigned short* Wqkvb = ws + 4 * M1;        // 3M (Wq|Wk|Wv rows)
    unsigned short* Wob   = ws + 7 * M1;        // 1M
    unsigned short* Qbf   = ws + 8 * M1;        // 4M  [bh][s][64]
    unsigned short* Kbf   = ws + 12 * M1;       // 4M  [bh][s][64]
    unsigned short* VTb   = ws + 16 * M1;       // 4M  [bh][64][s]
    unsigned short* AOb   = ws + 20 * M1;       // 4M  [b*s][1024]

    convert_all<<<4096, 256, 0, stream>>>(x, Wq, Wk, Wv, Wo, Xb, Wqkvb, Wob);

    // QKV projection (epilogue scatters Q,K row-major; V transposed)
    gemm_mfma<0><<<dim3(24, 32), 512, 0, stream>>>(Xb, Wqkvb, Qbf, Kbf, VTb, nullptr);

    // RoPE in place on bf16 Q/K
    rope_bf16<<<4096, 256, 0, stream>>>(Qbf, Kbf, pos);

    // flash attention (16-wave key-split blocks, counted-vmcnt 3-deep pipeline)
    flash_mfma<<<dim3(16, 32), 1024, 0, stream>>>(Qbf, Kbf, VTb, AOb);

    // output projection
    gemm_mfma<1><<<dim3(8, 32), 512, 0, stream>>>(AOb, Wob, nullptr, nullptr, nullptr, out);
}

// Round 26
// 101.180 us; speedup vs baseline: 1.2796x; 1.0592x over previous
//
#include <hip/hip_runtime.h>
#include <math.h>

#define SEQ   2048
#define BATCH 2
#define NH    16
#define DKD   64
#define DM    1024
#define MTOT  (BATCH*SEQ)   // 4096

typedef short bf16x8 __attribute__((ext_vector_type(8)));      // 8 bf16 (4 VGPR)
typedef float f32x4  __attribute__((ext_vector_type(4)));      // MFMA C/D
typedef unsigned short u16x4 __attribute__((ext_vector_type(4)));
typedef unsigned short u16x8 __attribute__((ext_vector_type(8)));

#define MFMA_B16(a,b,c) __builtin_amdgcn_mfma_f32_16x16x32_bf16((a),(b),(c),0,0,0)

__device__ __forceinline__ unsigned short f2bf(float f) {
    union { float f; unsigned int u; } v; v.f = f;
    unsigned int r = v.u + 0x7FFFu + ((v.u >> 16) & 1u);   // RNE
    return (unsigned short)(r >> 16);
}
__device__ __forceinline__ float bf2f(unsigned short h) {
    union { unsigned int u; float f; } v; v.u = ((unsigned int)h) << 16;
    return v.f;
}
__device__ __forceinline__ void gload16(const void* g, void* l) {
    __builtin_amdgcn_global_load_lds(
        (const __attribute__((address_space(1))) unsigned int*)g,
        (__attribute__((address_space(3))) unsigned int*)l, 16, 0, 0);
}

// ---------------- fp32 -> bf16: x + Wq + Wk + Wv + Wo, 32 B/thread ----------------
__global__ __launch_bounds__(256)
void convert_all(const float* __restrict__ x,  const float* __restrict__ Wq,
                 const float* __restrict__ Wk, const float* __restrict__ Wv,
                 const float* __restrict__ Wo,
                 unsigned short* __restrict__ Xb, unsigned short* __restrict__ Wqkvb,
                 unsigned short* __restrict__ Wob)
{
    int i = blockIdx.x * 256 + threadIdx.x;          // 0 .. 1M-1, each 8 floats
    const float* src;
    unsigned short* dst;
    size_t off;
    if (i < (1 << 19)) {                             // x: 4M floats = 512K groups
        src = x; dst = Xb; off = (size_t)i;
    } else {
        int j = i - (1 << 19);
        int wsel = j >> 17;                          // 0..3
        off = (size_t)(j & ((1 << 17) - 1));
        src = (wsel == 0) ? Wq : (wsel == 1) ? Wk : (wsel == 2) ? Wv : Wo;
        dst = (wsel < 3) ? Wqkvb + (size_t)wsel * (1u << 20) : Wob;
    }
    float4 v0 = ((const float4*)src)[off * 2];
    float4 v1 = ((const float4*)src)[off * 2 + 1];
    u16x8 o = { f2bf(v0.x), f2bf(v0.y), f2bf(v0.z), f2bf(v0.w),
                f2bf(v1.x), f2bf(v1.y), f2bf(v1.z), f2bf(v1.w) };
    *(u16x8*)&dst[off * 8] = o;
}

// ---------------- RoPE in place on bf16 Q/K  [bh][s][64], 16 B/thread ----------------
__global__ __launch_bounds__(256)
void rope_bf16(unsigned short* __restrict__ Qb, unsigned short* __restrict__ Kb,
               const int* __restrict__ pos)
{
    int idx = blockIdx.x * 256 + threadIdx.x;    // 0..1M-1 (Q then K), each 8 bf16
    int tsel = idx >> 19;
    int i = idx & ((1 << 19) - 1);
    unsigned short* base = tsel ? Kb : Qb;
    int d8 = i & 7;
    int s  = (i >> 3) & (SEQ - 1);
    float P = (float)pos[s];
    const float NEG_L2 = -0.41524101186092103f;  // -log2(10000)/32

    u16x8 v = *(u16x8*)&base[(size_t)i * 8];
    u16x8 o;
    #pragma unroll
    for (int k = 0; k < 4; ++k) {
        int pi = d8 * 4 + k;
        float ang = P * exp2f((float)pi * NEG_L2);
        float sn, cs;
        sincosf(ang, &sn, &cs);
        float e0 = bf2f(v[2*k]), e1 = bf2f(v[2*k + 1]);
        o[2*k]     = f2bf(e0 * cs - e1 * sn);
        o[2*k + 1] = f2bf(e0 * sn + e1 * cs);
    }
    *(u16x8*)&base[(size_t)i * 8] = o;
}

// ---------------- MFMA GEMM: 16-wave 64x16 sub-tiles ----------------
// C[M][N] = A[M][K] x B[N][K]^T, bf16 in / f32 acc; 128x128 tile, BK=32, 1024 thr.
// Wave (wm = w>>3, wn = w&7) owns a 64x16 output: 5 ds_read + 4 MFMA per round --
// the per-wave serial chain halved again vs the 8-wave version; 2 blocks/CU =
// 32 waves/CU resident. Staging: waves 0-7 stage A, 8-15 stage B (1 gload16 per
// thread, wave-uniform); 3-deep counted vmcnt(1). T2 read-swizzle unchanged.
// MODE 0: N=3072, epilogue scatters Q,K ([bh][s][d]) and V transposed ([bh][d][s])
// MODE 1: N=1024, epilogue writes fp32 row-major C
template<int MODE>
__global__ __launch_bounds__(1024, 8)
void gemm_mfma(const unsigned short* __restrict__ A, const unsigned short* __restrict__ B,
               unsigned short* __restrict__ Qb, unsigned short* __restrict__ Kb,
               unsigned short* __restrict__ VTb, float* __restrict__ Cf)
{
    const int t = threadIdx.x;
    const int w = t >> 6, l = t & 63, lid = l & 15, hi = (l >> 4) * 16;
    const int wm = w >> 3, wn = w & 7;               // 2 x 8 wave grid
    const int m0 = blockIdx.y * 128, n0 = blockIdx.x * 128;

    __shared__ __align__(16) char At[3][8192];       // [128 rows][32 k] bf16, 64 B rows
    __shared__ __align__(16) char Bt[3][8192];

    f32x4 acc[4];
    const f32x4 z4 = {0.f, 0.f, 0.f, 0.f};
    #pragma unroll
    for (int i = 0; i < 4; ++i) acc[i] = z4;

    const char* Ab = (const char*)A;
    const char* Bb = (const char*)B;

    auto stage = [&](int buf, int kt) {              // 1 gload16 per thread
        const int kbyte = kt * 64;
        int o   = (t & 511) * 16;                    // 0..8191
        int row = o >> 6, cb = o & 63;
        int sw  = ((row >> 1) & 3) << 4;             // T2: pre-swizzle global source
        if (t < 512)
            gload16(Ab + (size_t)(m0 + row) * 2048 + kbyte + (cb ^ sw),
                    At[buf] + w * 1024);
        else
            gload16(Bb + (size_t)(n0 + row) * 2048 + kbyte + (cb ^ sw),
                    Bt[buf] + (w - 8) * 1024);
    };

    const int NKT = DM / 32;                         // 32
    stage(0, 0);
    stage(1, 1);

    for (int kt = 0; kt < NKT; ++kt) {
        const int cur = kt % 3;
        if (kt == NKT - 1) asm volatile("s_waitcnt vmcnt(0)" ::: "memory");
        else               asm volatile("s_waitcnt vmcnt(1)" ::: "memory");
        __builtin_amdgcn_s_barrier();                // tile kt resident block-wide;
                                                     // buf[(kt+2)%3] free of readers
        if (kt + 2 < NKT) stage((kt + 2) % 3, kt + 2);

        bf16x8 af[4], bfr;
        #pragma unroll
        for (int mf = 0; mf < 4; ++mf) {
            int ar = wm * 64 + mf * 16 + lid;
            af[mf] = *(const bf16x8*)(At[cur] + ar * 64 + (hi ^ (((ar >> 1) & 3) << 4)));
        }
        {
            int br = wn * 16 + lid;
            bfr = *(const bf16x8*)(Bt[cur] + br * 64 + (hi ^ (((br >> 1) & 3) << 4)));
        }
        __builtin_amdgcn_s_setprio(1);
        #pragma unroll
        for (int mf = 0; mf < 4; ++mf)
            acc[mf] = MFMA_B16(af[mf], bfr, acc[mf]);
        __builtin_amdgcn_s_setprio(0);
    }

    if (MODE == 1) {
        #pragma unroll
        for (int mf = 0; mf < 4; ++mf) {
            int ncol = n0 + wn * 16 + lid;
            #pragma unroll
            for (int jj = 0; jj < 4; ++jj) {
                int mrow = m0 + wm * 64 + mf * 16 + (l >> 4) * 4 + jj;
                Cf[(size_t)mrow * DM + ncol] = acc[mf][jj];
            }
        }
    } else {
        const int z = n0 >> 10;                      // 0:Q 1:K 2:V
        const int nbase = n0 & 1023;
        #pragma unroll
        for (int mf = 0; mf < 4; ++mf) {
            int ncol = nbase + wn * 16 + lid;
            int h = ncol >> 6, d = ncol & 63;
            int mbase = m0 + wm * 64 + mf * 16 + (l >> 4) * 4;
            int b = mbase >> 11, s0v = mbase & 2047;
            if (z == 2) {
                u16x4 pk = { f2bf(acc[mf][0]), f2bf(acc[mf][1]),
                             f2bf(acc[mf][2]), f2bf(acc[mf][3]) };
                *(u16x4*)&VTb[((size_t)(b * NH + h) * DKD + d) * SEQ + s0v] = pk;
            } else {
                unsigned short* dst = (z == 0) ? Qb : Kb;
                #pragma unroll
                for (int jj = 0; jj < 4; ++jj)
                    dst[((size_t)(b * NH + h) * SEQ + (s0v + jj)) * DKD + d] =
                        f2bf(acc[mf][jj]);
            }
        }
    }
}

// ---------------- MFMA flash attention: key-split 16-wave blocks (exact R24) -------
__global__ __launch_bounds__(1024, 8)
void flash_mfma(const unsigned short* __restrict__ Qb, const unsigned short* __restrict__ Kb,
                const unsigned short* __restrict__ VTb, unsigned short* __restrict__ AOb)
{
    const int L  = blockIdx.y * 16 + blockIdx.x;     // 0..511
    const int g  = L >> 8, c = L & 255;
    const int j  = c & 15;
    const int bh = (g << 4) | (c >> 4);
    const int b = bh >> 4, h = bh & 15;
    const int qbA = g ? (30 - 2 * j) : (2 * j);
    const int qbB = qbA + 1;

    const int t = threadIdx.x;
    const int w8 = t >> 6, l = t & 63, lid = l & 15, hi = (l >> 4) * 16;
    const int h4 = l >> 4;
    const int tile = w8 >> 3, wq = (w8 >> 1) & 3, kh = w8 & 1;
    const int qbMy = tile ? qbB : qbA;
    const int ntMy = qbMy + 1;
    const int q0My = qbMy * 64;
    const int ntB  = qbB + 1;                        // loop bound (B = A+1), >= 2

    __shared__ __align__(16) char Kt[3][8192];
    __shared__ __align__(16) char Vt[3][8192];
    __shared__ __align__(16) char Pt[2][8192];       // per-tile P

    const char* Kbh = (const char*)(Kb  + (size_t)bh * SEQ * DKD);
    const char* Vbh = (const char*)(VTb + (size_t)bh * SEQ * DKD);
    const char* Qbh = (const char*)(Qb  + (size_t)bh * SEQ * DKD);

    const f32x4 z4 = {0.f, 0.f, 0.f, 0.f};
    const int qrow = wq * 16 + lid;
    const float CLOG = 0.18033688011112042f;     // log2(e)/8
    const float NMC  = -17.312340490667560f;     // -12*log2(e)

    bf16x8 onesv;
    #pragma unroll
    for (int i = 0; i < 8; ++i) onesv[i] = (short)0x3F80;   // bf16 1.0

    bf16x8 qf[2];
    qf[0] = *(const bf16x8*)(Qbh + (size_t)(q0My + qrow) * 128 + 0  + hi);
    qf[1] = *(const bf16x8*)(Qbh + (size_t)(q0My + qrow) * 128 + 64 + hi);

    f32x4 o[4], o5;
    #pragma unroll
    for (int nf = 0; nf < 4; ++nf) o[nf] = z4;
    o5 = z4;

    auto stage = [&](int buf, int kt) {
        if (t < 512) {
            int o_ = t * 16, row = o_ >> 7, cl = o_ & 127, sw = (row & 7) << 4;
            gload16(Kbh + (size_t)(kt * 64 + row) * 128 + (cl ^ sw),
                    Kt[buf] + w8 * 1024);
        } else {
            int o_ = (t - 512) * 16, row = o_ >> 7, cl = o_ & 127, sw = (row & 7) << 4;
            gload16(Vbh + (size_t)row * (SEQ * 2) + kt * 128 + (cl ^ sw),
                    Vt[buf] + (w8 - 8) * 1024);
        }
    };

    stage(0, 0);
    stage(1, 1);

    for (int kt = 0; kt < ntB; ++kt) {
        const int cur = kt % 3;

        if (kt == ntB - 1) asm volatile("s_waitcnt vmcnt(0)" ::: "memory");
        else               asm volatile("s_waitcnt vmcnt(1)" ::: "memory");
        __builtin_amdgcn_s_barrier();
        if (kt + 2 < ntB) stage((kt + 2) % 3, kt + 2);

        if (kt < ntMy) {
            f32x4 sf[2];
            __builtin_amdgcn_s_setprio(1);
            #pragma unroll
            for (int nf = 0; nf < 2; ++nf) {
                f32x4 a = z4;
                #pragma unroll
                for (int ks = 0; ks < 2; ++ks) {
                    int r  = kh * 32 + nf * 16 + lid;
                    int cb = ks * 64 + hi;
                    bf16x8 kfr = *(const bf16x8*)(Kt[cur] + r * 128 + (cb ^ ((r & 7) << 4)));
                    a = MFMA_B16(kfr, qf[ks], a);          // swapped operands
                }
                sf[nf] = a;
            }
            __builtin_amdgcn_s_setprio(0);

            if (kt == qbMy) {
                const int qloc = wq * 16 + lid;
                #pragma unroll
                for (int nf = 0; nf < 2; ++nf) {
                    #pragma unroll
                    for (int jj = 0; jj < 4; ++jj) {
                        int keyloc = kh * 32 + nf * 16 + h4 * 4 + jj;
                        if (keyloc > qloc) sf[nf][jj] = -1e30f;
                    }
                }
            }

            uint2 pk[2];
            #pragma unroll
            for (int nf = 0; nf < 2; ++nf) {
                float p0, p1, p2, p3;
                asm("v_exp_f32 %0, %1" : "=v"(p0) : "v"(fmaf(sf[nf][0], CLOG, NMC)));
                asm("v_exp_f32 %0, %1" : "=v"(p1) : "v"(fmaf(sf[nf][1], CLOG, NMC)));
                asm("v_exp_f32 %0, %1" : "=v"(p2) : "v"(fmaf(sf[nf][2], CLOG, NMC)));
                asm("v_exp_f32 %0, %1" : "=v"(p3) : "v"(fmaf(sf[nf][3], CLOG, NMC)));
                unsigned plo, phi;
                asm("v_cvt_pk_bf16_f32 %0, %1, %2" : "=v"(plo) : "v"(p0), "v"(p1));
                asm("v_cvt_pk_bf16_f32 %0, %1, %2" : "=v"(phi) : "v"(p2), "v"(p3));
                pk[nf].x = plo; pk[nf].y = phi;
            }

            {
                const int swz  = (lid & 7) << 4;
                char* base = Pt[tile] + qrow * 128;
                #pragma unroll
                for (int nf = 0; nf < 2; ++nf)
                    *(uint2*)(base + ((kh * 64 + nf * 32 + 8 * h4) ^ swz)) = pk[nf];
            }

            {
                int cb = kh * 64 + hi;
                bf16x8 pa = *(const bf16x8*)(Pt[tile] + qrow * 128 + (cb ^ ((qrow & 7) << 4)));
                __builtin_amdgcn_s_setprio(1);
                #pragma unroll
                for (int nf = 0; nf < 4; ++nf) {
                    int dr = nf * 16 + lid;
                    bf16x8 vb = *(const bf16x8*)(Vt[cur] + dr * 128 + (cb ^ ((dr & 7) << 4)));
                    o[nf] = MFMA_B16(pa, vb, o[nf]);
                }
                o5 = MFMA_B16(pa, onesv, o5);
                __builtin_amdgcn_s_setprio(0);
            }
        }
    }

    // ---- epilogue: merge key-half partials (waves w8, w8^1), normalize, store ----
    __syncthreads();                                 // K/V LDS now dead -> scratch
    const int ww = w8 >> 1;                          // pair index 0..7
    char* scr = (ww < 4) ? ((char*)Kt + ww * 5120)
                         : ((char*)Vt + (ww - 4) * 5120);
    if (kh == 1) {                                   // writer: 5 x float4 per lane
        #pragma unroll
        for (int nf = 0; nf < 4; ++nf)
            *(f32x4*)(scr + l * 80 + nf * 16) = o[nf];
        *(f32x4*)(scr + l * 80 + 64) = o5;
    }
    __syncthreads();
    if (kh == 0) {
        #pragma unroll
        for (int nf = 0; nf < 4; ++nf) {
            f32x4 po = *(const f32x4*)(scr + l * 80 + nf * 16);
            o[nf] += po;
        }
        f32x4 po5 = *(const f32x4*)(scr + l * 80 + 64);
        o5 += po5;

        float inv[4];
        #pragma unroll
        for (int jj = 0; jj < 4; ++jj) inv[jj] = 1.0f / o5[jj];
        #pragma unroll
        for (int nf = 0; nf < 4; ++nf)
            #pragma unroll
            for (int jj = 0; jj < 4; ++jj) {
                int srow = q0My + wq * 16 + h4 * 4 + jj;
                int col  = h * 64 + nf * 16 + lid;
                AOb[((size_t)b * SEQ + srow) * DM + col] = f2bf(o[nf][jj] * inv[jj]);
            }
    }
}

// ---------------- launch ----------------
extern "C" void kernel_launch(void* const* d_in, const int* in_sizes, int n_in,
                              void* d_out, int out_size, void* d_ws, size_t ws_size,
                              hipStream_t stream)
{
    const float* x   = (const float*)d_in[0];
    const int*   pos = (const int*)  d_in[1];
    const float* Wq  = (const float*)d_in[2];
    const float* Wk  = (const float*)d_in[3];
    const float* Wv  = (const float*)d_in[4];
    const float* Wo  = (const float*)d_in[5];
    float* out = (float*)d_out;

    const size_t M1 = 1u << 20;                 // 1M elements
    unsigned short* ws  = (unsigned short*)d_ws;
    unsigned short* Xb    = ws;                 // 4M
    unsigned short* Wqkvb = ws + 4 * M1;        // 3M (Wq|Wk|Wv rows)
    unsigned short* Wob   = ws + 7 * M1;        // 1M
    unsigned short* Qbf   = ws + 8 * M1;        // 4M  [bh][s][64]
    unsigned short* Kbf   = ws + 12 * M1;       // 4M  [bh][s][64]
    unsigned short* VTb   = ws + 16 * M1;       // 4M  [bh][64][s]
    unsigned short* AOb   = ws + 20 * M1;       // 4M  [b*s][1024]

    convert_all<<<4096, 256, 0, stream>>>(x, Wq, Wk, Wv, Wo, Xb, Wqkvb, Wob);

    // QKV projection (epilogue scatters Q,K row-major; V transposed)
    gemm_mfma<0><<<dim3(24, 32), 1024, 0, stream>>>(Xb, Wqkvb, Qbf, Kbf, VTb, nullptr);

    // RoPE in place on bf16 Q/K
    rope_bf16<<<4096, 256, 0, stream>>>(Qbf, Kbf, pos);

    // flash attention (16-wave key-split blocks, counted-vmcnt 3-deep pipeline)
    flash_mfma<<<dim3(16, 32), 1024, 0, stream>>>(Qbf, Kbf, VTb, AOb);

    // output projection
    gemm_mfma<1><<<dim3(8, 32), 1024, 0, stream>>>(AOb, Wob, nullptr, nullptr, nullptr, out);
}